// Round 2
// baseline (3146.382 us; speedup 1.0000x reference)
//
#include <hip/hip_runtime.h>
#include <hip/hip_bf16.h>
#include <math.h>

// ReformerAttention (LSH attention) on MI355X.
// B=4 T=4096 HID=768 H=12 D=64 n_hashes=2 n_buckets=32 bucket=128.
// Input dtype (bf16 vs f32) is DETECTED ON DEVICE (k_detect) and all
// input-reading kernels branch on the flag; internal buffers are bf16/f32/f64
// of my choosing. Bucket argmax path is f64 (rotations folded into W_qk).
//
// Workspace layout (bytes):
//   0           flag  int
//   256         WrotT f64 [768][384]         2,359,296
//   2,359,552   cls   u8  [48][8192]           393,216
//   2,752,768   stick u16 [48][8192]           786,432
//   3,539,200   lse_r f32 [48][2][4096]      1,572,864
//   5,112,064   qk    bf16[48][4096][64]    25,165,824  (reused as tmp after attn)
//   30,277,888  v     bf16[48][4096][64]    25,165,824  (reused as attn after k_attn)
//   55,443,712  o_r   bf16[48][2][4096][64] 50,331,648  (end 105,775,360)

__device__ __forceinline__ float bf_lo(unsigned int w) { return __uint_as_float(w << 16); }
__device__ __forceinline__ float bf_hi(unsigned int w) { return __uint_as_float(w & 0xffff0000u); }
__device__ __forceinline__ float load_in(const void* p, size_t i, bool f32) {
  return f32 ? ((const float*)p)[i]
             : __bfloat162float(((const __hip_bfloat16*)p)[i]);
}

// ---------------------------------------------------------------- dtype detect
// bf16 N(0,1) data: bits 7..14 of each 32-bit word (low element's exponent)
// cluster in [100,141]. f32 data: those bits are mantissa bits -> uniform.
__global__ void k_detect(const unsigned int* __restrict__ X, int* __restrict__ flag) {
  if (threadIdx.x == 0 && blockIdx.x == 0) {
    int vote = 0;
    for (int i = 0; i < 64; ++i) {
      unsigned int e = (X[i] >> 7) & 0xffu;
      vote += (e >= 100u && e <= 141u) ? 1 : 0;
    }
    *flag = (vote < 32) ? 1 : 0;   // 1 => inputs are f32
  }
}

// ---------------------------------------------------------------- fold rotations
// WrotT[c][row] = sum_f rot[f, h, i] * Wqk[hh*64+f, c],  row = hh*32 + h*16 + i
__global__ __launch_bounds__(256) void k_build_wrot(
    const void* __restrict__ Wqk, const void* __restrict__ rot,
    double* __restrict__ WrotT, const int* __restrict__ flag) {
  const bool f32in = (*flag != 0);
  int idx = blockIdx.x * 256 + threadIdx.x;
  if (idx >= 768 * 384) return;
  int row = idx % 384;
  int c   = idx / 384;
  int hh = row >> 5, hi = row & 31;
  double s = 0.0;
  for (int f = 0; f < 64; ++f) {
    double rv = (double)load_in(rot, f * 32 + hi, f32in);
    double wv = (double)load_in(Wqk, (size_t)(hh * 64 + f) * 768 + c, f32in);
    s = fma(rv, wv, s);
  }
  WrotT[(size_t)c * 384 + row] = s;
}

// ---------------------------------------------------------------- bucket argmax
__global__ __launch_bounds__(384) void k_bucket(
    const void* __restrict__ X, const double* __restrict__ WrotT,
    unsigned char* __restrict__ cls, const int* __restrict__ flag) {
  const bool f32in = (*flag != 0);
  __shared__ double Xs[16][32];
  __shared__ double Ss[16][384];
  const int b  = blockIdx.x >> 8;
  const int t0 = (blockIdx.x & 255) * 16;
  const int tid = threadIdx.x;
  double acc[16];
  #pragma unroll
  for (int i = 0; i < 16; ++i) acc[i] = 0.0;
  for (int k0 = 0; k0 < 768; k0 += 32) {
    __syncthreads();
    for (int e = tid; e < 512; e += 384) {
      int tt = e >> 5, kk = e & 31;
      Xs[tt][kk] = (double)load_in(X, ((size_t)(b * 4096 + t0 + tt)) * 768 + k0 + kk, f32in);
    }
    __syncthreads();
    for (int kk = 0; kk < 32; ++kk) {
      double w = WrotT[(size_t)(k0 + kk) * 384 + tid];
      #pragma unroll
      for (int tt = 0; tt < 16; ++tt) acc[tt] = fma(Xs[tt][kk], w, acc[tt]);
    }
  }
  #pragma unroll
  for (int tt = 0; tt < 16; ++tt) Ss[tt][tid] = acc[tt];
  __syncthreads();
  const int tt = tid / 24;
  const int g  = tid % 24;
  const int hh = g >> 1, h = g & 1;
  const double* s = &Ss[tt][hh * 32 + h * 16];
  double mx = -1.0e300;
  #pragma unroll
  for (int i = 0; i < 16; ++i) {
    double a = s[i];
    mx = fmax(mx, fmax(a, -a));
  }
  int amax = 0;
  #pragma unroll
  for (int i = 15; i >= 0; --i) if (-s[i] == mx) amax = 16 + i;
  #pragma unroll
  for (int i = 15; i >= 0; --i) if (s[i] == mx) amax = i;
  cls[(size_t)(b * 12 + hh) * 8192 + h * 4096 + t0 + tt] = (unsigned char)(h * 32 + amax);
}

// ---------------------------------------------------------------- stable counting sort
__global__ __launch_bounds__(64) void k_sort(
    const unsigned char* __restrict__ clsg,
    unsigned short* __restrict__ stick) {
  __shared__ uint32_t lc32[2048];
  __shared__ int cnt[64];
  __shared__ int offs[64];
  const int row = blockIdx.x;
  const int tid = threadIdx.x;
  const uint32_t* cr = (const uint32_t*)(clsg + ((size_t)row << 13));
  for (int e = tid; e < 2048; e += 64) lc32[e] = cr[e];
  __syncthreads();
  const unsigned char* lc = (const unsigned char*)lc32;
  const unsigned char c = (unsigned char)tid;
  int n = 0;
  for (int j = 0; j < 8192; ++j) n += (lc[j] == c) ? 1 : 0;
  cnt[tid] = n;
  __syncthreads();
  if (tid == 0) {
    int sacc = 0;
    for (int i = 0; i < 64; ++i) { offs[i] = sacc; sacc += cnt[i]; }
  }
  __syncthreads();
  int off = offs[tid];
  unsigned short* out = stick + ((size_t)row << 13);
  for (int j = 0; j < 8192; ++j) {
    if (lc[j] == c) { out[off] = (unsigned short)j; ++off; }
  }
}

// ---------------------------------------------------------------- 768-K GEMM
// C[m,n] = sum_k A[m,k]*Wt[n,k] (+bias[n]).
// layout 0: C flat [m][n]; layout 1: merged heads [(b*12+hh)][t][f].
// a_ext: A is an external input (dtype per flag); Wt/bias always external.
// out_ext: C is d_out (dtype per flag); else internal bf16.
__global__ __launch_bounds__(256) void k_gemm768(
    const void* __restrict__ A, const void* __restrict__ Wt,
    const void* __restrict__ bias, void* __restrict__ Cout,
    int layout, int a_ext, int out_ext, const int* __restrict__ flag) {
  const bool f32in = (*flag != 0);
  const bool aF32 = a_ext && f32in;
  const bool oF32 = out_ext && f32in;
  __shared__ float As[16][68];
  __shared__ float Ws[16][68];
  const int bm = blockIdx.x, bn = blockIdx.y;
  const int tid = threadIdx.x;
  const int tx = tid & 15, ty = tid >> 4;
  float acc[4][4];
  #pragma unroll
  for (int i = 0; i < 4; ++i)
    #pragma unroll
    for (int j = 0; j < 4; ++j) acc[i][j] = 0.0f;
  const int r = tid >> 2, k4 = (tid & 3) * 4;
  const size_t arow = (size_t)(bm * 64 + r) * 768 + k4;
  const size_t wrow = (size_t)(bn * 64 + r) * 768 + k4;
  for (int kt = 0; kt < 768; kt += 16) {
    __syncthreads();
    float a0, a1, a2, a3, w0, w1, w2, w3;
    if (aF32) {
      float4 fa = *(const float4*)((const float*)A + arow + kt);
      a0 = fa.x; a1 = fa.y; a2 = fa.z; a3 = fa.w;
    } else {
      uint2 wa = *(const uint2*)((const __hip_bfloat16*)A + arow + kt);
      a0 = bf_lo(wa.x); a1 = bf_hi(wa.x); a2 = bf_lo(wa.y); a3 = bf_hi(wa.y);
    }
    if (f32in) {
      float4 fw = *(const float4*)((const float*)Wt + wrow + kt);
      w0 = fw.x; w1 = fw.y; w2 = fw.z; w3 = fw.w;
    } else {
      uint2 ww = *(const uint2*)((const __hip_bfloat16*)Wt + wrow + kt);
      w0 = bf_lo(ww.x); w1 = bf_hi(ww.x); w2 = bf_lo(ww.y); w3 = bf_hi(ww.y);
    }
    As[k4 + 0][r] = a0; As[k4 + 1][r] = a1; As[k4 + 2][r] = a2; As[k4 + 3][r] = a3;
    Ws[k4 + 0][r] = w0; Ws[k4 + 1][r] = w1; Ws[k4 + 2][r] = w2; Ws[k4 + 3][r] = w3;
    __syncthreads();
    #pragma unroll
    for (int k = 0; k < 16; ++k) {
      float4 a = *(const float4*)&As[k][ty * 4];
      float4 w = *(const float4*)&Ws[k][tx * 4];
      acc[0][0] = fmaf(a.x, w.x, acc[0][0]); acc[0][1] = fmaf(a.x, w.y, acc[0][1]);
      acc[0][2] = fmaf(a.x, w.z, acc[0][2]); acc[0][3] = fmaf(a.x, w.w, acc[0][3]);
      acc[1][0] = fmaf(a.y, w.x, acc[1][0]); acc[1][1] = fmaf(a.y, w.y, acc[1][1]);
      acc[1][2] = fmaf(a.y, w.z, acc[1][2]); acc[1][3] = fmaf(a.y, w.w, acc[1][3]);
      acc[2][0] = fmaf(a.z, w.x, acc[2][0]); acc[2][1] = fmaf(a.z, w.y, acc[2][1]);
      acc[2][2] = fmaf(a.z, w.z, acc[2][2]); acc[2][3] = fmaf(a.z, w.w, acc[2][3]);
      acc[3][0] = fmaf(a.w, w.x, acc[3][0]); acc[3][1] = fmaf(a.w, w.y, acc[3][1]);
      acc[3][2] = fmaf(a.w, w.z, acc[3][2]); acc[3][3] = fmaf(a.w, w.w, acc[3][3]);
    }
  }
  #pragma unroll
  for (int rr = 0; rr < 4; ++rr) {
    int mrow = bm * 64 + ty * 4 + rr;
    #pragma unroll
    for (int cc = 0; cc < 4; ++cc) {
      int n = bn * 64 + tx * 4 + cc;
      float val = acc[rr][cc];
      if (bias != nullptr) val += load_in(bias, n, f32in);
      size_t addr;
      if (layout == 0) {
        addr = (size_t)mrow * 768 + n;
      } else {
        int b2 = mrow >> 12, t2 = mrow & 4095, hh = n >> 6, f = n & 63;
        addr = ((((size_t)(b2 * 12 + hh)) << 12) + t2) * 64 + f;
      }
      if (oF32) ((float*)Cout)[addr] = val;
      else      ((__hip_bfloat16*)Cout)[addr] = __float2bfloat16(val);
    }
  }
}

// ---------------------------------------------------------------- chunked LSH attention
// One block per (bh, chunk). 128 threads = one query each; 256 keys.
// K is normalized on the fly via per-row 1/||k|| staged in LDS.
__global__ __launch_bounds__(128) void k_attn(
    const __hip_bfloat16* __restrict__ qk,
    const __hip_bfloat16* __restrict__ vv,
    const unsigned short* __restrict__ stick,
    const void* __restrict__ mask,
    __hip_bfloat16* __restrict__ o_r,
    float* __restrict__ lse_r,
    const int* __restrict__ flag) {
  const bool f32in = (*flag != 0);
  __shared__ unsigned short Tk[256];
  __shared__ float Mk[256];
  __shared__ float Nk[256];
  const int bh = blockIdx.x >> 6;
  const int ci = blockIdx.x & 63;
  const int b  = bh / 12;
  const int tid = threadIdx.x;
  const int prev = (ci + 63) & 63;
  const unsigned short* srow = stick + ((size_t)bh << 13);

  for (int j = tid; j < 256; j += 128) {
    int chunk = (j < 128) ? ci : prev;
    int s = srow[chunk * 128 + (j & 127)];
    int t = s & 4095;
    Tk[j] = (unsigned short)t;
    Mk[j] = load_in(mask, b * 4096 + t, f32in);
  }
  __syncthreads();
  for (int j = tid; j < 256; j += 128) {
    int tj = Tk[j];
    const uint4* kp = (const uint4*)(qk + ((((size_t)bh << 12) + tj) << 6));
    float s = 0.0f;
    #pragma unroll
    for (int i = 0; i < 8; ++i) {
      uint4 w = kp[i];
      float e0 = bf_lo(w.x), e1 = bf_hi(w.x), e2 = bf_lo(w.y), e3 = bf_hi(w.y);
      float e4 = bf_lo(w.z), e5 = bf_hi(w.z), e6 = bf_lo(w.w), e7 = bf_hi(w.w);
      s += e0*e0 + e1*e1 + e2*e2 + e3*e3 + e4*e4 + e5*e5 + e6*e6 + e7*e7;
    }
    Nk[j] = 1.0f / fmaxf(sqrtf(s), 1e-12f);
  }

  const int sq = srow[ci * 128 + tid];
  const int tq = sq & 4095;
  const int rq = sq >> 12;
  float q[64];
  {
    const uint4* qp = (const uint4*)(qk + ((((size_t)bh << 12) + tq) << 6));
    #pragma unroll
    for (int i = 0; i < 8; ++i) {
      uint4 w = qp[i];
      q[i * 8 + 0] = bf_lo(w.x); q[i * 8 + 1] = bf_hi(w.x);
      q[i * 8 + 2] = bf_lo(w.y); q[i * 8 + 3] = bf_hi(w.y);
      q[i * 8 + 4] = bf_lo(w.z); q[i * 8 + 5] = bf_hi(w.z);
      q[i * 8 + 6] = bf_lo(w.w); q[i * 8 + 7] = bf_hi(w.w);
    }
  }
  const bool mq = (load_in(mask, b * 4096 + tq, f32in) != 0.0f);
  __syncthreads();

  float m = -1.0e9f, l = 0.0f;
  float o[64];
  #pragma unroll
  for (int f = 0; f < 64; ++f) o[f] = 0.0f;

  for (int j = 0; j < 256; ++j) {
    const int tj = Tk[j];
    const uint4* kp = (const uint4*)(qk + ((((size_t)bh << 12) + tj) << 6));
    float d0 = 0.f, d1 = 0.f, d2 = 0.f, d3 = 0.f;
    #pragma unroll
    for (int i = 0; i < 8; ++i) {
      uint4 w = kp[i];
      d0 = fmaf(q[i * 8 + 0], bf_lo(w.x), d0);
      d1 = fmaf(q[i * 8 + 1], bf_hi(w.x), d1);
      d2 = fmaf(q[i * 8 + 2], bf_lo(w.y), d2);
      d3 = fmaf(q[i * 8 + 3], bf_hi(w.y), d3);
      d0 = fmaf(q[i * 8 + 4], bf_lo(w.z), d0);
      d1 = fmaf(q[i * 8 + 5], bf_hi(w.z), d1);
      d2 = fmaf(q[i * 8 + 6], bf_lo(w.w), d2);
      d3 = fmaf(q[i * 8 + 7], bf_hi(w.w), d3);
    }
    float dv = ((d0 + d1) + (d2 + d3)) * 0.125f * Nk[j];
    if (!(mq && (Mk[j] != 0.0f))) dv = -1.0e9f;   // pad mask
    if (tq == tj) dv = -5.0e4f;                   // self-attn (overrides pad)
    const float mn = fmaxf(m, dv);
    const float sc = __expf(m - mn);
    const float p  = __expf(dv - mn);
    l = l * sc + p;
    const uint4* vp = (const uint4*)(vv + ((((size_t)bh << 12) + tj) << 6));
    #pragma unroll
    for (int i = 0; i < 8; ++i) {
      uint4 w = vp[i];
      o[i * 8 + 0] = fmaf(o[i * 8 + 0], sc, p * bf_lo(w.x));
      o[i * 8 + 1] = fmaf(o[i * 8 + 1], sc, p * bf_hi(w.x));
      o[i * 8 + 2] = fmaf(o[i * 8 + 2], sc, p * bf_lo(w.y));
      o[i * 8 + 3] = fmaf(o[i * 8 + 3], sc, p * bf_hi(w.y));
      o[i * 8 + 4] = fmaf(o[i * 8 + 4], sc, p * bf_lo(w.z));
      o[i * 8 + 5] = fmaf(o[i * 8 + 5], sc, p * bf_hi(w.z));
      o[i * 8 + 6] = fmaf(o[i * 8 + 6], sc, p * bf_lo(w.w));
      o[i * 8 + 7] = fmaf(o[i * 8 + 7], sc, p * bf_hi(w.w));
    }
    m = mn;
  }
  const float invl = 1.0f / l;
  __hip_bfloat16* orow = o_r + ((((size_t)(bh * 2 + rq)) << 12) + tq) * 64;
  #pragma unroll
  for (int f = 0; f < 64; ++f) orow[f] = __float2bfloat16(o[f] * invl);
  lse_r[(((size_t)(bh * 2 + rq)) << 12) + tq] = m + __logf(l);
}

// ---------------------------------------------------------------- combine hash rounds
__global__ __launch_bounds__(256) void k_combine(
    const __hip_bfloat16* __restrict__ o_r,
    const float* __restrict__ lse_r,
    __hip_bfloat16* __restrict__ attn) {
  int idx = blockIdx.x * 256 + threadIdx.x;
  if (idx >= 48 * 4096 * 64) return;
  int f = idx & 63;
  int t = (idx >> 6) & 4095;
  int bh = idx >> 18;
  float l0 = lse_r[((size_t)(bh * 2 + 0) << 12) + t];
  float l1 = lse_r[((size_t)(bh * 2 + 1) << 12) + t];
  float mm = fmaxf(l0, l1);
  float e0 = __expf(l0 - mm), e1 = __expf(l1 - mm);
  float inv = 1.0f / (e0 + e1);
  float o0 = __bfloat162float(o_r[(((size_t)(bh * 2 + 0) << 12) + t) * 64 + f]);
  float o1 = __bfloat162float(o_r[(((size_t)(bh * 2 + 1) << 12) + t) * 64 + f]);
  float res = (e0 * o0 + e1 * o1) * inv;
  int b = bh / 12, hh = bh % 12;
  attn[((size_t)(b * 4096 + t)) * 768 + hh * 64 + f] = __float2bfloat16(res);
}

extern "C" void kernel_launch(void* const* d_in, const int* in_sizes, int n_in,
                              void* d_out, int out_size, void* d_ws, size_t ws_size,
                              hipStream_t stream) {
  (void)in_sizes; (void)n_in; (void)out_size; (void)ws_size;
  const void* X    = d_in[0];
  const void* mask = d_in[1];
  const void* Wqk  = d_in[2];
  const void* Wv   = d_in[3];
  const void* rot  = d_in[4];
  const void* Wto  = d_in[5];
  const void* bto  = d_in[6];
  const void* Wo   = d_in[7];
  const void* bo   = d_in[8];

  char* ws = (char*)d_ws;
  int*            flag  = (int*)(ws);
  double*         WrotT = (double*)(ws + 256);
  unsigned char*  cls   = (unsigned char*)(ws + 2359552);
  unsigned short* stick = (unsigned short*)(ws + 2752768);
  float*          lse_r = (float*)(ws + 3539200);
  __hip_bfloat16* qk    = (__hip_bfloat16*)(ws + 5112064);
  __hip_bfloat16* v     = (__hip_bfloat16*)(ws + 30277888);
  __hip_bfloat16* o_r   = (__hip_bfloat16*)(ws + 55443712);
  __hip_bfloat16* attn  = v;    // v dead after k_attn
  __hip_bfloat16* tmp   = qk;   // qk dead after k_attn

  k_detect<<<1, 64, 0, stream>>>((const unsigned int*)X, flag);
  k_build_wrot<<<1152, 256, 0, stream>>>(Wqk, rot, WrotT, flag);
  k_bucket<<<1024, 384, 0, stream>>>(X, WrotT, cls, flag);
  k_sort<<<48, 64, 0, stream>>>(cls, stick);
  k_gemm768<<<dim3(256, 12), 256, 0, stream>>>(X, Wqk, nullptr, qk, 1, 1, 0, flag);
  k_gemm768<<<dim3(256, 12), 256, 0, stream>>>(X, Wv,  nullptr, v,  1, 1, 0, flag);
  k_attn<<<3072, 128, 0, stream>>>(qk, v, stick, mask, o_r, lse_r, flag);
  k_combine<<<49152, 256, 0, stream>>>(o_r, lse_r, attn);
  k_gemm768<<<dim3(256, 12), 256, 0, stream>>>(attn, Wto, bto, tmp, 0, 0, 0, flag);
  k_gemm768<<<dim3(256, 12), 256, 0, stream>>>(tmp, Wo, bo, d_out, 0, 0, 1, flag);
}

// Round 3
// 1549.249 us; speedup vs baseline: 2.0309x; 2.0309x over previous
//
#include <hip/hip_runtime.h>
#include <hip/hip_bf16.h>
#include <math.h>

// ReformerAttention (LSH attention) on MI355X — MFMA round.
// B=4 T=4096 HID=768 H=12 D=64 n_hashes=2 n_buckets=32 bucket=128.
//
// Workspace layout (bytes), peak 103,809,280 (< proven 105,775,360):
//   0           flag   256
//   256         stick  u16[48][8192]        786,432   [k_sort -> k_attn]
//   786,688     lse_r  f32[48*2][4096]    1,572,864   [k_attn -> k_combine]
//   2,359,552   nk     f32[48][4096]        786,432   [k_norm -> k_attn]
//   3,145,984   qk     bf16[48][4096][64] 25,165,824  [proj -> attn; then tmp]
//   28,311,808  v      bf16[48][4096][64] 25,165,824  [proj -> attn; then attn-out]
//   53,477,632  o_r    bf16[96][4096][64] 50,331,648  [attn -> combine]
//   overlays inside o_r region (all dead before k_attn writes o_r):
//     WrotT @53,477,632 (2,359,296) | cls @55,836,928 (393,216)
//     Wqkb @56,230,144 | Wvb @57,409,792 (1,179,648 each)
//     Xb   @58,589,440 (25,165,824; ends 83,755,264)
//   after k_combine (o_r dead): Wtob @53,477,632, Wob @54,657,280

typedef __attribute__((ext_vector_type(8))) short bf16x8;
typedef __attribute__((ext_vector_type(4))) float f32x4;

__device__ __forceinline__ float bf_lo(unsigned int w) { return __uint_as_float(w << 16); }
__device__ __forceinline__ float bf_hi(unsigned int w) { return __uint_as_float(w & 0xffff0000u); }
__device__ __forceinline__ float load_in(const void* p, size_t i, bool f32) {
  return f32 ? ((const float*)p)[i]
             : __bfloat162float(((const __hip_bfloat16*)p)[i]);
}
__device__ __forceinline__ unsigned short f2bf(float x) {
  __hip_bfloat16 h = __float2bfloat16(x);
  return *reinterpret_cast<unsigned short*>(&h);
}
__device__ __forceinline__ float bf2f(unsigned short u) { return __uint_as_float(((unsigned int)u) << 16); }

// ---------------------------------------------------------------- dtype detect
__global__ void k_detect(const unsigned int* __restrict__ X, int* __restrict__ flag) {
  if (threadIdx.x == 0 && blockIdx.x == 0) {
    int vote = 0;
    for (int i = 0; i < 64; ++i) {
      unsigned int e = (X[i] >> 7) & 0xffu;
      vote += (e >= 100u && e <= 141u) ? 1 : 0;
    }
    *flag = (vote < 32) ? 1 : 0;   // 1 => inputs are f32
  }
}

// ---------------------------------------------------------------- convert input -> bf16
__global__ __launch_bounds__(256) void k_convert(
    const void* __restrict__ src, unsigned short* __restrict__ dst, int n,
    const int* __restrict__ flag) {
  const bool f32in = (*flag != 0);
  int i = blockIdx.x * 256 + threadIdx.x;
  if (i >= n) return;
  if (f32in) dst[i] = f2bf(((const float*)src)[i]);
  else       dst[i] = ((const unsigned short*)src)[i];
}

// ---------------------------------------------------------------- fold rotations (f64)
__global__ __launch_bounds__(256) void k_build_wrot(
    const void* __restrict__ Wqk, const void* __restrict__ rot,
    double* __restrict__ WrotT, const int* __restrict__ flag) {
  const bool f32in = (*flag != 0);
  int idx = blockIdx.x * 256 + threadIdx.x;
  if (idx >= 768 * 384) return;
  int row = idx % 384;
  int c   = idx / 384;
  int hh = row >> 5, hi = row & 31;
  double s = 0.0;
  for (int f = 0; f < 64; ++f) {
    double rv = (double)load_in(rot, f * 32 + hi, f32in);
    double wv = (double)load_in(Wqk, (size_t)(hh * 64 + f) * 768 + c, f32in);
    s = fma(rv, wv, s);
  }
  WrotT[(size_t)c * 384 + row] = s;
}

// ---------------------------------------------------------------- bucket argmax (f64)
__global__ __launch_bounds__(384) void k_bucket(
    const void* __restrict__ X, const double* __restrict__ WrotT,
    unsigned char* __restrict__ cls, const int* __restrict__ flag) {
  const bool f32in = (*flag != 0);
  __shared__ double Xs[16][32];
  __shared__ double Ss[16][384];
  const int b  = blockIdx.x >> 8;
  const int t0 = (blockIdx.x & 255) * 16;
  const int tid = threadIdx.x;
  double acc[16];
  #pragma unroll
  for (int i = 0; i < 16; ++i) acc[i] = 0.0;
  for (int k0 = 0; k0 < 768; k0 += 32) {
    __syncthreads();
    for (int e = tid; e < 512; e += 384) {
      int tt = e >> 5, kk = e & 31;
      Xs[tt][kk] = (double)load_in(X, ((size_t)(b * 4096 + t0 + tt)) * 768 + k0 + kk, f32in);
    }
    __syncthreads();
    for (int kk = 0; kk < 32; ++kk) {
      double w = WrotT[(size_t)(k0 + kk) * 384 + tid];
      #pragma unroll
      for (int tt = 0; tt < 16; ++tt) acc[tt] = fma(Xs[tt][kk], w, acc[tt]);
    }
  }
  #pragma unroll
  for (int tt = 0; tt < 16; ++tt) Ss[tt][tid] = acc[tt];
  __syncthreads();
  const int tt = tid / 24;
  const int g  = tid % 24;
  const int hh = g >> 1, h = g & 1;
  const double* s = &Ss[tt][hh * 32 + h * 16];
  double mx = -1.0e300;
  #pragma unroll
  for (int i = 0; i < 16; ++i) {
    double a = s[i];
    mx = fmax(mx, fmax(a, -a));
  }
  int amax = 0;
  #pragma unroll
  for (int i = 15; i >= 0; --i) if (-s[i] == mx) amax = 16 + i;
  #pragma unroll
  for (int i = 15; i >= 0; --i) if (s[i] == mx) amax = i;
  cls[(size_t)(b * 12 + hh) * 8192 + h * 4096 + t0 + tt] = (unsigned char)(h * 32 + amax);
}

// ---------------------------------------------------------------- stable counting sort
__global__ __launch_bounds__(64) void k_sort(
    const unsigned char* __restrict__ clsg,
    unsigned short* __restrict__ stick) {
  __shared__ uint32_t lc32[2048];
  __shared__ int cnt[64];
  __shared__ int offs[64];
  const int row = blockIdx.x;
  const int tid = threadIdx.x;
  const uint32_t* cr = (const uint32_t*)(clsg + ((size_t)row << 13));
  for (int e = tid; e < 2048; e += 64) lc32[e] = cr[e];
  __syncthreads();
  const unsigned char* lc = (const unsigned char*)lc32;
  const unsigned char c = (unsigned char)tid;
  int n = 0;
  for (int j = 0; j < 8192; ++j) n += (lc[j] == c) ? 1 : 0;
  cnt[tid] = n;
  __syncthreads();
  if (tid == 0) {
    int sacc = 0;
    for (int i = 0; i < 64; ++i) { offs[i] = sacc; sacc += cnt[i]; }
  }
  __syncthreads();
  int off = offs[tid];
  unsigned short* out = stick + ((size_t)row << 13);
  for (int j = 0; j < 8192; ++j) {
    if (lc[j] == c) { out[off] = (unsigned short)j; ++off; }
  }
}

// ---------------------------------------------------------------- MFMA GEMM, K=768
// C[m,n] = sum_k A[m,k]*W[n,k] (+bias). A [M][768], W [N][768] bf16 row-major.
// 128x128 tile, BK=32, 256 thr = 4 waves (2x2), wave tile 64x64 (4x4 of 16x16x32).
__global__ __launch_bounds__(256) void k_gemm_mfma(
    const unsigned short* __restrict__ A, const unsigned short* __restrict__ W,
    const void* __restrict__ bias, void* __restrict__ Cout,
    int layout, int out_ext, const int* __restrict__ flag) {
  const bool f32in = (*flag != 0);
  const bool oF32 = out_ext && f32in;
  __shared__ unsigned short As[128 * 40];
  __shared__ unsigned short Bs[128 * 40];
  const int tid = threadIdx.x;
  const int bm = blockIdx.x, bn = blockIdx.y;
  const int w = tid >> 6, lane = tid & 63;
  const int l15 = lane & 15, lq = lane >> 4;
  const int wm = (w >> 1) * 64, wn = (w & 1) * 64;
  const int r4 = tid >> 2, c4 = tid & 3;
  const unsigned short* Ag = A + (size_t)(bm * 128 + r4) * 768 + c4 * 8;
  const unsigned short* Bg = W + (size_t)(bn * 128 + r4) * 768 + c4 * 8;
  f32x4 acc[4][4];
  #pragma unroll
  for (int i = 0; i < 4; ++i)
    #pragma unroll
    for (int j = 0; j < 4; ++j) acc[i][j] = (f32x4){0.f, 0.f, 0.f, 0.f};
  uint4 pa0 = *(const uint4*)(Ag);
  uint4 pa1 = *(const uint4*)(Ag + 64 * 768);
  uint4 pb0 = *(const uint4*)(Bg);
  uint4 pb1 = *(const uint4*)(Bg + 64 * 768);
  for (int kt = 0; kt < 24; ++kt) {
    __syncthreads();
    *(uint4*)&As[r4 * 40 + c4 * 8] = pa0;
    *(uint4*)&As[(r4 + 64) * 40 + c4 * 8] = pa1;
    *(uint4*)&Bs[r4 * 40 + c4 * 8] = pb0;
    *(uint4*)&Bs[(r4 + 64) * 40 + c4 * 8] = pb1;
    __syncthreads();
    if (kt < 23) {
      int off = (kt + 1) * 32;
      pa0 = *(const uint4*)(Ag + off);
      pa1 = *(const uint4*)(Ag + 64 * 768 + off);
      pb0 = *(const uint4*)(Bg + off);
      pb1 = *(const uint4*)(Bg + 64 * 768 + off);
    }
    bf16x8 af[4], bfr[4];
    #pragma unroll
    for (int mt = 0; mt < 4; ++mt)
      af[mt] = *(const bf16x8*)&As[(wm + mt * 16 + l15) * 40 + lq * 8];
    #pragma unroll
    for (int nt = 0; nt < 4; ++nt)
      bfr[nt] = *(const bf16x8*)&Bs[(wn + nt * 16 + l15) * 40 + lq * 8];
    #pragma unroll
    for (int mt = 0; mt < 4; ++mt)
      #pragma unroll
      for (int nt = 0; nt < 4; ++nt)
        acc[mt][nt] = __builtin_amdgcn_mfma_f32_16x16x32_bf16(af[mt], bfr[nt], acc[mt][nt], 0, 0, 0);
  }
  #pragma unroll
  for (int mt = 0; mt < 4; ++mt) {
    #pragma unroll
    for (int nt = 0; nt < 4; ++nt) {
      #pragma unroll
      for (int reg = 0; reg < 4; ++reg) {
        int m = bm * 128 + wm + mt * 16 + lq * 4 + reg;
        int n = bn * 128 + wn + nt * 16 + l15;
        float val = acc[mt][nt][reg];
        if (bias != nullptr) val += load_in(bias, n, f32in);
        if (layout == 0) {
          size_t addr = (size_t)m * 768 + n;
          if (oF32) ((float*)Cout)[addr] = val;
          else      ((unsigned short*)Cout)[addr] = f2bf(val);
        } else {
          int b2 = m >> 12, t2 = m & 4095, hh = n >> 6, f = n & 63;
          ((unsigned short*)Cout)[((((size_t)(b2 * 12 + hh)) << 12) + t2) * 64 + f] = f2bf(val);
        }
      }
    }
  }
}

// ---------------------------------------------------------------- key norms
__global__ __launch_bounds__(256) void k_norm(
    const unsigned short* __restrict__ qk, float* __restrict__ nk) {
  int row = blockIdx.x * 32 + (threadIdx.x >> 3);
  int cs = threadIdx.x & 7;
  const uint4* p = (const uint4*)(qk + (size_t)row * 64);
  uint4 wv = p[cs];
  float s = 0.f;
  float e;
  e = bf_lo(wv.x); s += e * e;  e = bf_hi(wv.x); s += e * e;
  e = bf_lo(wv.y); s += e * e;  e = bf_hi(wv.y); s += e * e;
  e = bf_lo(wv.z); s += e * e;  e = bf_hi(wv.z); s += e * e;
  e = bf_lo(wv.w); s += e * e;  e = bf_hi(wv.w); s += e * e;
  s += __shfl_xor(s, 1, 64);
  s += __shfl_xor(s, 2, 64);
  s += __shfl_xor(s, 4, 64);
  if (cs == 0) nk[row] = 1.0f / fmaxf(sqrtf(s), 1e-12f);
}

// ---------------------------------------------------------------- MFMA LSH attention
// One block (256 thr = 4 waves) per (bh, chunk). Wave w owns query rows
// 32w..32w+31. Keys = 256 (chunk + prev) processed as 4 k-tiles of 64 with
// online softmax. S and PV on MFMA 16x16x32 bf16; P round-trips LDS strip.
__global__ __launch_bounds__(256) void k_attn_mfma(
    const unsigned short* __restrict__ qk,
    const unsigned short* __restrict__ vv,
    const unsigned short* __restrict__ stick,
    const void* __restrict__ mask,
    const float* __restrict__ nk,
    unsigned short* __restrict__ o_r,
    float* __restrict__ lse_r,
    const int* __restrict__ flag) {
  const bool f32in = (*flag != 0);
  __shared__ unsigned short Qs[128 * 72];      // queries (chunk rows)
  __shared__ unsigned short Ks[64 * 72];       // current key tile
  __shared__ unsigned short Vt[64 * 72];       // V^T of current tile: Vt[n][j]
  __shared__ unsigned short Ps[4 * 32 * 72];   // per-wave P strip; Ps[0..4608) doubles as Vs
  __shared__ unsigned short Tq[128];
  __shared__ unsigned short Tkv[64];
  __shared__ float Nkv[64];
  unsigned short* Vs = Ps;                     // swizzled V-row staging, 64*72 els

  const int tid = threadIdx.x;
  const int bh = blockIdx.x >> 6;
  const int ci = blockIdx.x & 63;
  const int b  = bh / 12;
  const int prev = (ci + 63) & 63;
  const int w = tid >> 6, lane = tid & 63;
  const int l15 = lane & 15, lq = lane >> 4;
  const unsigned short* srow = stick + ((size_t)bh << 13);
  const int jrow = tid >> 3, cs = tid & 7;

  // ---- gather Q (128 rows) + per-query metadata
  #pragma unroll
  for (int pass = 0; pass < 4; ++pass) {
    int r = jrow + pass * 32;
    int s = srow[ci * 128 + r];
    int t = s & 4095;
    uint4 qw = ((const uint4*)(qk + ((((size_t)bh << 12) + t) << 6)))[cs];
    *(uint4*)&Qs[r * 72 + cs * 8] = qw;
    if (cs == 0) {
      float mv = load_in(mask, b * 4096 + t, f32in);
      Tq[r] = (unsigned short)(s | ((mv != 0.0f) ? 0 : 0x8000));
    }
  }
  __syncthreads();

  unsigned short tqr[2][4];
  #pragma unroll
  for (int mt = 0; mt < 2; ++mt)
    #pragma unroll
    for (int reg = 0; reg < 4; ++reg)
      tqr[mt][reg] = Tq[w * 32 + mt * 16 + lq * 4 + reg];

  float m_run[2][4], l_run[2][4];
  f32x4 oacc[2][4];
  #pragma unroll
  for (int mt = 0; mt < 2; ++mt)
    #pragma unroll
    for (int reg = 0; reg < 4; ++reg) { m_run[mt][reg] = -3.0e38f; l_run[mt][reg] = 0.0f; }
  #pragma unroll
  for (int mt = 0; mt < 2; ++mt)
    #pragma unroll
    for (int nto = 0; nto < 4; ++nto) oacc[mt][nto] = (f32x4){0.f, 0.f, 0.f, 0.f};

  for (int kt = 0; kt < 4; ++kt) {
    __syncthreads();   // prior tile's S/PV reads of Ks/Vt + Ps(0,1) done
    // ---- gather K rows + swizzled V rows + per-key metadata
    #pragma unroll
    for (int pass = 0; pass < 2; ++pass) {
      int j = jrow + pass * 32;
      int chunk = (kt < 2) ? ci : prev;
      int s = srow[chunk * 128 + (kt & 1) * 64 + j];
      int t = s & 4095;
      const uint4* kb = (const uint4*)(qk + ((((size_t)bh << 12) + t) << 6));
      *(uint4*)&Ks[j * 72 + cs * 8] = kb[cs];
      const uint4* vb = (const uint4*)(vv + ((((size_t)bh << 12) + t) << 6));
      int sw = (cs ^ (j & 7) ^ (j >> 3)) & 7;
      *(uint4*)&Vs[j * 72 + sw * 8] = vb[cs];
      if (cs == 0) {
        float mv = load_in(mask, b * 4096 + t, f32in);
        Tkv[j] = (unsigned short)(t | ((mv != 0.0f) ? 0 : 0x8000));
        Nkv[j] = nk[((size_t)bh << 12) + t] * 0.125f;
      }
    }
    __syncthreads();   // gather visible

    // ---- transpose Vs(swizzled) -> Vt[n][j]
    #pragma unroll
    for (int i = 0; i < 8; ++i) {
      int cp = w * 8 + i;            // col pair (2cp, 2cp+1)
      int q8 = cp >> 2;              // stored chunk of the pair
      int sw = (q8 ^ (lane & 7) ^ (lane >> 3)) & 7;
      uint32_t wv = *(const uint32_t*)&Vs[lane * 72 + sw * 8 + ((2 * cp) & 7)];
      Vt[(2 * cp) * 72 + lane]     = (unsigned short)(wv & 0xffff);
      Vt[(2 * cp + 1) * 72 + lane] = (unsigned short)(wv >> 16);
    }

    // ---- S = Q . K^T  (per wave: 32 rows x 64 keys)
    f32x4 sacc[2][4];
    #pragma unroll
    for (int mt = 0; mt < 2; ++mt)
      #pragma unroll
      for (int nt = 0; nt < 4; ++nt) sacc[mt][nt] = (f32x4){0.f, 0.f, 0.f, 0.f};
    #pragma unroll
    for (int ks = 0; ks < 2; ++ks) {
      bf16x8 af[2];
      #pragma unroll
      for (int mt = 0; mt < 2; ++mt)
        af[mt] = *(const bf16x8*)&Qs[(w * 32 + mt * 16 + l15) * 72 + ks * 32 + lq * 8];
      #pragma unroll
      for (int nt = 0; nt < 4; ++nt) {
        bf16x8 bfr = *(const bf16x8*)&Ks[(nt * 16 + l15) * 72 + ks * 32 + lq * 8];
        #pragma unroll
        for (int mt = 0; mt < 2; ++mt)
          sacc[mt][nt] = __builtin_amdgcn_mfma_f32_16x16x32_bf16(af[mt], bfr, sacc[mt][nt], 0, 0, 0);
      }
    }

    // ---- masked scores + online softmax
    unsigned short tkc[4];
    float nkc[4];
    #pragma unroll
    for (int nt = 0; nt < 4; ++nt) {
      tkc[nt] = Tkv[nt * 16 + l15];
      nkc[nt] = Nkv[nt * 16 + l15];
    }
    float dv[2][4][4];
    #pragma unroll
    for (int mt = 0; mt < 2; ++mt)
      #pragma unroll
      for (int nt = 0; nt < 4; ++nt)
        #pragma unroll
        for (int reg = 0; reg < 4; ++reg) {
          float x = sacc[mt][nt][reg] * nkc[nt];
          unsigned short ts = tqr[mt][reg];
          if (((tkc[nt] | ts) & 0x8000) != 0) x = -1.0e9f;
          if (((tkc[nt] ^ ts) & 0x0fff) == 0) x = -5.0e4f;
          dv[mt][nt][reg] = x;
        }
    float mn[2][4], scv[2][4];
    #pragma unroll
    for (int mt = 0; mt < 2; ++mt)
      #pragma unroll
      for (int reg = 0; reg < 4; ++reg) {
        float rm = fmaxf(fmaxf(dv[mt][0][reg], dv[mt][1][reg]),
                         fmaxf(dv[mt][2][reg], dv[mt][3][reg]));
        rm = fmaxf(rm, __shfl_xor(rm, 1, 64));
        rm = fmaxf(rm, __shfl_xor(rm, 2, 64));
        rm = fmaxf(rm, __shfl_xor(rm, 4, 64));
        rm = fmaxf(rm, __shfl_xor(rm, 8, 64));
        float mnew = fmaxf(m_run[mt][reg], rm);
        scv[mt][reg] = __expf(m_run[mt][reg] - mnew);
        m_run[mt][reg] = mnew;
        mn[mt][reg] = mnew;
      }
    #pragma unroll
    for (int mt = 0; mt < 2; ++mt)
      #pragma unroll
      for (int nt = 0; nt < 4; ++nt)
        #pragma unroll
        for (int reg = 0; reg < 4; ++reg)
          dv[mt][nt][reg] = __expf(dv[mt][nt][reg] - mn[mt][reg]);
    #pragma unroll
    for (int mt = 0; mt < 2; ++mt)
      #pragma unroll
      for (int reg = 0; reg < 4; ++reg) {
        float rs = ((dv[mt][0][reg] + dv[mt][1][reg]) + (dv[mt][2][reg] + dv[mt][3][reg]));
        rs += __shfl_xor(rs, 1, 64);
        rs += __shfl_xor(rs, 2, 64);
        rs += __shfl_xor(rs, 4, 64);
        rs += __shfl_xor(rs, 8, 64);
        l_run[mt][reg] = l_run[mt][reg] * scv[mt][reg] + rs;
      }
    #pragma unroll
    for (int mt = 0; mt < 2; ++mt)
      #pragma unroll
      for (int nto = 0; nto < 4; ++nto)
        #pragma unroll
        for (int reg = 0; reg < 4; ++reg)
          oacc[mt][nto][reg] *= scv[mt][reg];

    __syncthreads();   // all waves past Vs reads before P writes clobber Ps[0..1]

    // ---- P -> LDS strip (C-layout -> A-layout round trip)
    #pragma unroll
    for (int mt = 0; mt < 2; ++mt)
      #pragma unroll
      for (int nt = 0; nt < 4; ++nt)
        #pragma unroll
        for (int reg = 0; reg < 4; ++reg)
          Ps[w * 2304 + (mt * 16 + lq * 4 + reg) * 72 + nt * 16 + l15] = f2bf(dv[mt][nt][reg]);

    // ---- O += P . V
    #pragma unroll
    for (int ks = 0; ks < 2; ++ks) {
      bf16x8 pf[2];
      #pragma unroll
      for (int mt = 0; mt < 2; ++mt)
        pf[mt] = *(const bf16x8*)&Ps[w * 2304 + (mt * 16 + l15) * 72 + ks * 32 + lq * 8];
      #pragma unroll
      for (int nto = 0; nto < 4; ++nto) {
        bf16x8 vf = *(const bf16x8*)&Vt[(nto * 16 + l15) * 72 + ks * 32 + lq * 8];
        #pragma unroll
        for (int mt = 0; mt < 2; ++mt)
          oacc[mt][nto] = __builtin_amdgcn_mfma_f32_16x16x32_bf16(pf[mt], vf, oacc[mt][nto], 0, 0, 0);
      }
    }
  }

  // ---- epilogue: 1/l scale, LSE, coalesced scatter through LDS
  float invl[2][4];
  #pragma unroll
  for (int mt = 0; mt < 2; ++mt)
    #pragma unroll
    for (int reg = 0; reg < 4; ++reg) {
      float lr = l_run[mt][reg];
      invl[mt][reg] = 1.0f / lr;
      if (l15 == 0) {
        int Rr = w * 32 + mt * 16 + lq * 4 + reg;
        int s = Tq[Rr];
        int tq0 = s & 4095, rq0 = (s >> 12) & 1;
        lse_r[(((size_t)(bh * 2 + rq0)) << 12) + tq0] = m_run[mt][reg] + __logf(lr);
      }
    }
  #pragma unroll
  for (int mt = 0; mt < 2; ++mt)
    #pragma unroll
    for (int nto = 0; nto < 4; ++nto)
      #pragma unroll
      for (int reg = 0; reg < 4; ++reg)
        Ps[w * 2304 + (mt * 16 + lq * 4 + reg) * 72 + nto * 16 + l15] =
            f2bf(oacc[mt][nto][reg] * invl[mt][reg]);
  #pragma unroll
  for (int pass = 0; pass < 4; ++pass) {
    int rl = pass * 8 + (lane >> 3);
    int s = Tq[w * 32 + rl];
    int tq0 = s & 4095, rq0 = (s >> 12) & 1;
    uint4 ov = *(const uint4*)&Ps[w * 2304 + rl * 72 + (lane & 7) * 8];
    *(uint4*)(o_r + ((((size_t)(bh * 2 + rq0)) << 12) + tq0) * 64 + (lane & 7) * 8) = ov;
  }
}

// ---------------------------------------------------------------- combine hash rounds
__global__ __launch_bounds__(256) void k_combine(
    const unsigned short* __restrict__ o_r,
    const float* __restrict__ lse_r,
    unsigned short* __restrict__ attn) {
  int idx = blockIdx.x * 256 + threadIdx.x;
  if (idx >= 48 * 4096 * 64) return;
  int f = idx & 63;
  int t = (idx >> 6) & 4095;
  int bh = idx >> 18;
  float l0 = lse_r[((size_t)(bh * 2 + 0) << 12) + t];
  float l1 = lse_r[((size_t)(bh * 2 + 1) << 12) + t];
  float mm = fmaxf(l0, l1);
  float e0 = __expf(l0 - mm), e1 = __expf(l1 - mm);
  float inv = 1.0f / (e0 + e1);
  float o0 = bf2f(o_r[(((size_t)(bh * 2 + 0) << 12) + t) * 64 + f]);
  float o1 = bf2f(o_r[(((size_t)(bh * 2 + 1) << 12) + t) * 64 + f]);
  float res = (e0 * o0 + e1 * o1) * inv;
  int b = bh / 12, hh = bh % 12;
  attn[((size_t)(b * 4096 + t)) * 768 + hh * 64 + f] = f2bf(res);
}

extern "C" void kernel_launch(void* const* d_in, const int* in_sizes, int n_in,
                              void* d_out, int out_size, void* d_ws, size_t ws_size,
                              hipStream_t stream) {
  (void)in_sizes; (void)n_in; (void)out_size; (void)ws_size;
  const void* X    = d_in[0];
  const void* mask = d_in[1];
  const void* Wqk  = d_in[2];
  const void* Wv   = d_in[3];
  const void* rot  = d_in[4];
  const void* Wto  = d_in[5];
  const void* bto  = d_in[6];
  const void* Wo   = d_in[7];
  const void* bo   = d_in[8];

  char* ws = (char*)d_ws;
  int*            flag  = (int*)(ws);
  unsigned short* stick = (unsigned short*)(ws + 256);
  float*          lse_r = (float*)(ws + 786688);
  float*          nk    = (float*)(ws + 2359552);
  unsigned short* qk    = (unsigned short*)(ws + 3145984);
  unsigned short* v     = (unsigned short*)(ws + 28311808);
  unsigned short* o_r   = (unsigned short*)(ws + 53477632);
  // overlays (dead before k_attn writes o_r):
  double*         WrotT = (double*)(ws + 53477632);
  unsigned char*  cls   = (unsigned char*)(ws + 55836928);
  unsigned short* Wqkb  = (unsigned short*)(ws + 56230144);
  unsigned short* Wvb   = (unsigned short*)(ws + 57409792);
  unsigned short* Xb    = (unsigned short*)(ws + 58589440);
  // after k_combine (o_r dead):
  unsigned short* Wtob  = (unsigned short*)(ws + 53477632);
  unsigned short* Wob   = (unsigned short*)(ws + 54657280);
  unsigned short* attn  = v;    // v dead after k_attn
  unsigned short* tmp   = qk;   // qk dead after k_attn

  k_detect<<<1, 64, 0, stream>>>((const unsigned int*)X, flag);
  k_convert<<<49152, 256, 0, stream>>>(X, Xb, 12582912, flag);
  k_convert<<<2304, 256, 0, stream>>>(Wqk, Wqkb, 589824, flag);
  k_convert<<<2304, 256, 0, stream>>>(Wv, Wvb, 589824, flag);
  k_build_wrot<<<1152, 256, 0, stream>>>(Wqk, rot, WrotT, flag);
  k_bucket<<<1024, 384, 0, stream>>>(X, WrotT, cls, flag);
  k_sort<<<48, 64, 0, stream>>>(cls, stick);
  k_gemm_mfma<<<dim3(128, 6), 256, 0, stream>>>(Xb, Wqkb, nullptr, qk, 1, 0, flag);
  k_gemm_mfma<<<dim3(128, 6), 256, 0, stream>>>(Xb, Wvb,  nullptr, v,  1, 0, flag);
  k_norm<<<6144, 256, 0, stream>>>(qk, nk);
  k_attn_mfma<<<3072, 256, 0, stream>>>(qk, v, stick, mask, nk, o_r, lse_r, flag);
  k_combine<<<49152, 256, 0, stream>>>(o_r, lse_r, attn);
  k_convert<<<2304, 256, 0, stream>>>(Wto, Wtob, 589824, flag);
  k_convert<<<2304, 256, 0, stream>>>(Wo, Wob, 589824, flag);
  k_gemm_mfma<<<dim3(128, 6), 256, 0, stream>>>(attn, Wtob, bto, tmp, 0, 0, flag);
  k_gemm_mfma<<<dim3(128, 6), 256, 0, stream>>>(tmp, Wob, bo, d_out, 0, 1, flag);
}

// Round 4
// 956.031 us; speedup vs baseline: 3.2911x; 1.6205x over previous
//
#include <hip/hip_runtime.h>
#include <hip/hip_bf16.h>
#include <math.h>

// ReformerAttention (LSH attention) on MI355X — MFMA round + parallel sort.
// B=4 T=4096 HID=768 H=12 D=64 n_hashes=2 n_buckets=32 bucket=128.
//
// Workspace layout (bytes), peak 103,809,280:
//   0           flag   256
//   256         stick  u16[48][8192]        786,432   [k_sort -> k_attn]
//   786,688     lse_r  f32[48*2][4096]    1,572,864   [k_attn -> k_combine]
//   2,359,552   nk     f32[48][4096]        786,432   [k_norm -> k_attn]
//   3,145,984   qk     bf16[48][4096][64] 25,165,824  [proj -> attn; then tmp]
//   28,311,808  v      bf16[48][4096][64] 25,165,824  [proj -> attn; then attn-out]
//   53,477,632  o_r    bf16[96][4096][64] 50,331,648  [attn -> combine]
//   overlays inside o_r region (all dead before k_attn writes o_r):
//     WrotT @53,477,632 (2,359,296) | cls @55,836,928 (393,216)
//     Wqkb @56,230,144 | Wvb @57,409,792 (1,179,648 each)
//     Xb   @58,589,440 (25,165,824; ends 83,755,264)
//   after k_combine (o_r dead): Wtob @53,477,632, Wob @54,657,280

typedef __attribute__((ext_vector_type(8))) short bf16x8;
typedef __attribute__((ext_vector_type(4))) float f32x4;

__device__ __forceinline__ float bf_lo(unsigned int w) { return __uint_as_float(w << 16); }
__device__ __forceinline__ float bf_hi(unsigned int w) { return __uint_as_float(w & 0xffff0000u); }
__device__ __forceinline__ float load_in(const void* p, size_t i, bool f32) {
  return f32 ? ((const float*)p)[i]
             : __bfloat162float(((const __hip_bfloat16*)p)[i]);
}
__device__ __forceinline__ unsigned short f2bf(float x) {
  __hip_bfloat16 h = __float2bfloat16(x);
  return *reinterpret_cast<unsigned short*>(&h);
}
__device__ __forceinline__ float bf2f(unsigned short u) { return __uint_as_float(((unsigned int)u) << 16); }

// ---------------------------------------------------------------- dtype detect
__global__ void k_detect(const unsigned int* __restrict__ X, int* __restrict__ flag) {
  if (threadIdx.x == 0 && blockIdx.x == 0) {
    int vote = 0;
    for (int i = 0; i < 64; ++i) {
      unsigned int e = (X[i] >> 7) & 0xffu;
      vote += (e >= 100u && e <= 141u) ? 1 : 0;
    }
    *flag = (vote < 32) ? 1 : 0;   // 1 => inputs are f32
  }
}

// ---------------------------------------------------------------- convert input -> bf16
__global__ __launch_bounds__(256) void k_convert(
    const void* __restrict__ src, unsigned short* __restrict__ dst, int n,
    const int* __restrict__ flag) {
  const bool f32in = (*flag != 0);
  int i = blockIdx.x * 256 + threadIdx.x;
  if (i >= n) return;
  if (f32in) dst[i] = f2bf(((const float*)src)[i]);
  else       dst[i] = ((const unsigned short*)src)[i];
}

// ---------------------------------------------------------------- fold rotations (f64)
__global__ __launch_bounds__(256) void k_build_wrot(
    const void* __restrict__ Wqk, const void* __restrict__ rot,
    double* __restrict__ WrotT, const int* __restrict__ flag) {
  const bool f32in = (*flag != 0);
  int idx = blockIdx.x * 256 + threadIdx.x;
  if (idx >= 768 * 384) return;
  int row = idx % 384;
  int c   = idx / 384;
  int hh = row >> 5, hi = row & 31;
  double s = 0.0;
  for (int f = 0; f < 64; ++f) {
    double rv = (double)load_in(rot, f * 32 + hi, f32in);
    double wv = (double)load_in(Wqk, (size_t)(hh * 64 + f) * 768 + c, f32in);
    s = fma(rv, wv, s);
  }
  WrotT[(size_t)c * 384 + row] = s;
}

// ---------------------------------------------------------------- bucket argmax (f64)
__global__ __launch_bounds__(384) void k_bucket(
    const void* __restrict__ X, const double* __restrict__ WrotT,
    unsigned char* __restrict__ cls, const int* __restrict__ flag) {
  const bool f32in = (*flag != 0);
  __shared__ double Xs[16][32];
  __shared__ double Ss[16][384];
  const int b  = blockIdx.x >> 8;
  const int t0 = (blockIdx.x & 255) * 16;
  const int tid = threadIdx.x;
  double acc[16];
  #pragma unroll
  for (int i = 0; i < 16; ++i) acc[i] = 0.0;
  for (int k0 = 0; k0 < 768; k0 += 32) {
    __syncthreads();
    for (int e = tid; e < 512; e += 384) {
      int tt = e >> 5, kk = e & 31;
      Xs[tt][kk] = (double)load_in(X, ((size_t)(b * 4096 + t0 + tt)) * 768 + k0 + kk, f32in);
    }
    __syncthreads();
    for (int kk = 0; kk < 32; ++kk) {
      double w = WrotT[(size_t)(k0 + kk) * 384 + tid];
      #pragma unroll
      for (int tt = 0; tt < 16; ++tt) acc[tt] = fma(Xs[tt][kk], w, acc[tt]);
    }
  }
  #pragma unroll
  for (int tt = 0; tt < 16; ++tt) Ss[tt][tid] = acc[tt];
  __syncthreads();
  const int tt = tid / 24;
  const int g  = tid % 24;
  const int hh = g >> 1, h = g & 1;
  const double* s = &Ss[tt][hh * 32 + h * 16];
  double mx = -1.0e300;
  #pragma unroll
  for (int i = 0; i < 16; ++i) {
    double a = s[i];
    mx = fmax(mx, fmax(a, -a));
  }
  int amax = 0;
  #pragma unroll
  for (int i = 15; i >= 0; --i) if (-s[i] == mx) amax = 16 + i;
  #pragma unroll
  for (int i = 15; i >= 0; --i) if (s[i] == mx) amax = i;
  cls[(size_t)(b * 12 + hh) * 8192 + h * 4096 + t0 + tt] = (unsigned char)(h * 32 + amax);
}

// ---------------------------------------------------------------- parallel stable counting sort
// One block (1024 thr = 16 waves) per row. Element j = g*64+lane, 128 groups.
// Same-class lane mask via 6 ballots -> per-group rank + per-(group,class)
// counts; prefix over groups per class; exclusive scan over classes; scatter.
// pos = classbase[c] + groups-before-me count + rank  == stable (bucket,pos) order.
__global__ __launch_bounds__(1024) void k_sort(
    const unsigned char* __restrict__ clsg,
    unsigned short* __restrict__ stick) {
  __shared__ unsigned short cntg[128 * 64];   // [group][class], 16 KB
  __shared__ int classbase[64];
  const int row = blockIdx.x;
  const int tid = threadIdx.x;
  const int wave = tid >> 6, lane = tid & 63;
  const unsigned char* cr = clsg + ((size_t)row << 13);

  for (int i = tid; i < 128 * 64 / 2; i += 1024) ((uint32_t*)cntg)[i] = 0;
  __syncthreads();

  unsigned char myc[8], myrank[8];
  const unsigned long long ltmask = (lane == 0) ? 0ull : (~0ull >> (64 - lane));
  #pragma unroll
  for (int chunk = 0; chunk < 8; ++chunk) {
    int g = chunk * 16 + wave;
    int j = g * 64 + lane;
    int c = cr[j];
    unsigned long long same = ~0ull;
    #pragma unroll
    for (int bit = 0; bit < 6; ++bit) {
      unsigned long long bm = __ballot((c >> bit) & 1);
      same &= ((c >> bit) & 1) ? bm : ~bm;
    }
    int rank = __popcll(same & ltmask);
    if (rank == 0) cntg[g * 64 + c] = (unsigned short)__popcll(same);
    myc[chunk] = (unsigned char)c;
    myrank[chunk] = (unsigned char)rank;
  }
  __syncthreads();
  if (tid < 64) {               // per-class exclusive prefix over 128 groups
    int run = 0;
    for (int g = 0; g < 128; ++g) {
      int t = cntg[g * 64 + tid];
      cntg[g * 64 + tid] = (unsigned short)run;
      run += t;
    }
    classbase[tid] = run;       // class totals for now
  }
  __syncthreads();
  if (tid == 0) {               // exclusive scan over 64 classes
    int run = 0;
    for (int c = 0; c < 64; ++c) { int t = classbase[c]; classbase[c] = run; run += t; }
  }
  __syncthreads();
  unsigned short* out = stick + ((size_t)row << 13);
  #pragma unroll
  for (int chunk = 0; chunk < 8; ++chunk) {
    int g = chunk * 16 + wave;
    int j = g * 64 + lane;
    int c = myc[chunk];
    int pos = classbase[c] + cntg[g * 64 + c] + myrank[chunk];
    out[pos] = (unsigned short)j;
  }
}

// ---------------------------------------------------------------- MFMA GEMM, K=768
__global__ __launch_bounds__(256) void k_gemm_mfma(
    const unsigned short* __restrict__ A, const unsigned short* __restrict__ W,
    const void* __restrict__ bias, void* __restrict__ Cout,
    int layout, int out_ext, const int* __restrict__ flag) {
  const bool f32in = (*flag != 0);
  const bool oF32 = out_ext && f32in;
  __shared__ unsigned short As[128 * 40];
  __shared__ unsigned short Bs[128 * 40];
  const int tid = threadIdx.x;
  const int bm = blockIdx.x, bn = blockIdx.y;
  const int w = tid >> 6, lane = tid & 63;
  const int l15 = lane & 15, lq = lane >> 4;
  const int wm = (w >> 1) * 64, wn = (w & 1) * 64;
  const int r4 = tid >> 2, c4 = tid & 3;
  const unsigned short* Ag = A + (size_t)(bm * 128 + r4) * 768 + c4 * 8;
  const unsigned short* Bg = W + (size_t)(bn * 128 + r4) * 768 + c4 * 8;
  f32x4 acc[4][4];
  #pragma unroll
  for (int i = 0; i < 4; ++i)
    #pragma unroll
    for (int j = 0; j < 4; ++j) acc[i][j] = (f32x4){0.f, 0.f, 0.f, 0.f};
  uint4 pa0 = *(const uint4*)(Ag);
  uint4 pa1 = *(const uint4*)(Ag + 64 * 768);
  uint4 pb0 = *(const uint4*)(Bg);
  uint4 pb1 = *(const uint4*)(Bg + 64 * 768);
  for (int kt = 0; kt < 24; ++kt) {
    __syncthreads();
    *(uint4*)&As[r4 * 40 + c4 * 8] = pa0;
    *(uint4*)&As[(r4 + 64) * 40 + c4 * 8] = pa1;
    *(uint4*)&Bs[r4 * 40 + c4 * 8] = pb0;
    *(uint4*)&Bs[(r4 + 64) * 40 + c4 * 8] = pb1;
    __syncthreads();
    if (kt < 23) {
      int off = (kt + 1) * 32;
      pa0 = *(const uint4*)(Ag + off);
      pa1 = *(const uint4*)(Ag + 64 * 768 + off);
      pb0 = *(const uint4*)(Bg + off);
      pb1 = *(const uint4*)(Bg + 64 * 768 + off);
    }
    bf16x8 af[4], bfr[4];
    #pragma unroll
    for (int mt = 0; mt < 4; ++mt)
      af[mt] = *(const bf16x8*)&As[(wm + mt * 16 + l15) * 40 + lq * 8];
    #pragma unroll
    for (int nt = 0; nt < 4; ++nt)
      bfr[nt] = *(const bf16x8*)&Bs[(wn + nt * 16 + l15) * 40 + lq * 8];
    #pragma unroll
    for (int mt = 0; mt < 4; ++mt)
      #pragma unroll
      for (int nt = 0; nt < 4; ++nt)
        acc[mt][nt] = __builtin_amdgcn_mfma_f32_16x16x32_bf16(af[mt], bfr[nt], acc[mt][nt], 0, 0, 0);
  }
  #pragma unroll
  for (int mt = 0; mt < 4; ++mt) {
    #pragma unroll
    for (int nt = 0; nt < 4; ++nt) {
      #pragma unroll
      for (int reg = 0; reg < 4; ++reg) {
        int m = bm * 128 + wm + mt * 16 + lq * 4 + reg;
        int n = bn * 128 + wn + nt * 16 + l15;
        float val = acc[mt][nt][reg];
        if (bias != nullptr) val += load_in(bias, n, f32in);
        if (layout == 0) {
          size_t addr = (size_t)m * 768 + n;
          if (oF32) ((float*)Cout)[addr] = val;
          else      ((unsigned short*)Cout)[addr] = f2bf(val);
        } else {
          int b2 = m >> 12, t2 = m & 4095, hh = n >> 6, f = n & 63;
          ((unsigned short*)Cout)[((((size_t)(b2 * 12 + hh)) << 12) + t2) * 64 + f] = f2bf(val);
        }
      }
    }
  }
}

// ---------------------------------------------------------------- key norms
__global__ __launch_bounds__(256) void k_norm(
    const unsigned short* __restrict__ qk, float* __restrict__ nk) {
  int row = blockIdx.x * 32 + (threadIdx.x >> 3);
  int cs = threadIdx.x & 7;
  const uint4* p = (const uint4*)(qk + (size_t)row * 64);
  uint4 wv = p[cs];
  float s = 0.f;
  float e;
  e = bf_lo(wv.x); s += e * e;  e = bf_hi(wv.x); s += e * e;
  e = bf_lo(wv.y); s += e * e;  e = bf_hi(wv.y); s += e * e;
  e = bf_lo(wv.z); s += e * e;  e = bf_hi(wv.z); s += e * e;
  e = bf_lo(wv.w); s += e * e;  e = bf_hi(wv.w); s += e * e;
  s += __shfl_xor(s, 1, 64);
  s += __shfl_xor(s, 2, 64);
  s += __shfl_xor(s, 4, 64);
  if (cs == 0) nk[row] = 1.0f / fmaxf(sqrtf(s), 1e-12f);
}

// ---------------------------------------------------------------- MFMA LSH attention
__global__ __launch_bounds__(256) void k_attn_mfma(
    const unsigned short* __restrict__ qk,
    const unsigned short* __restrict__ vv,
    const unsigned short* __restrict__ stick,
    const void* __restrict__ mask,
    const float* __restrict__ nk,
    unsigned short* __restrict__ o_r,
    float* __restrict__ lse_r,
    const int* __restrict__ flag) {
  const bool f32in = (*flag != 0);
  __shared__ unsigned short Qs[128 * 72];
  __shared__ unsigned short Ks[64 * 72];
  __shared__ unsigned short Vt[64 * 72];
  __shared__ unsigned short Ps[4 * 32 * 72];
  __shared__ unsigned short Tq[128];
  __shared__ unsigned short Tkv[64];
  __shared__ float Nkv[64];
  unsigned short* Vs = Ps;

  const int tid = threadIdx.x;
  const int bh = blockIdx.x >> 6;
  const int ci = blockIdx.x & 63;
  const int b  = bh / 12;
  const int prev = (ci + 63) & 63;
  const int w = tid >> 6, lane = tid & 63;
  const int l15 = lane & 15, lq = lane >> 4;
  const unsigned short* srow = stick + ((size_t)bh << 13);
  const int jrow = tid >> 3, cs = tid & 7;

  #pragma unroll
  for (int pass = 0; pass < 4; ++pass) {
    int r = jrow + pass * 32;
    int s = srow[ci * 128 + r];
    int t = s & 4095;
    uint4 qw = ((const uint4*)(qk + ((((size_t)bh << 12) + t) << 6)))[cs];
    *(uint4*)&Qs[r * 72 + cs * 8] = qw;
    if (cs == 0) {
      float mv = load_in(mask, b * 4096 + t, f32in);
      Tq[r] = (unsigned short)(s | ((mv != 0.0f) ? 0 : 0x8000));
    }
  }
  __syncthreads();

  unsigned short tqr[2][4];
  #pragma unroll
  for (int mt = 0; mt < 2; ++mt)
    #pragma unroll
    for (int reg = 0; reg < 4; ++reg)
      tqr[mt][reg] = Tq[w * 32 + mt * 16 + lq * 4 + reg];

  float m_run[2][4], l_run[2][4];
  f32x4 oacc[2][4];
  #pragma unroll
  for (int mt = 0; mt < 2; ++mt)
    #pragma unroll
    for (int reg = 0; reg < 4; ++reg) { m_run[mt][reg] = -3.0e38f; l_run[mt][reg] = 0.0f; }
  #pragma unroll
  for (int mt = 0; mt < 2; ++mt)
    #pragma unroll
    for (int nto = 0; nto < 4; ++nto) oacc[mt][nto] = (f32x4){0.f, 0.f, 0.f, 0.f};

  for (int kt = 0; kt < 4; ++kt) {
    __syncthreads();
    #pragma unroll
    for (int pass = 0; pass < 2; ++pass) {
      int j = jrow + pass * 32;
      int chunk = (kt < 2) ? ci : prev;
      int s = srow[chunk * 128 + (kt & 1) * 64 + j];
      int t = s & 4095;
      const uint4* kb = (const uint4*)(qk + ((((size_t)bh << 12) + t) << 6));
      *(uint4*)&Ks[j * 72 + cs * 8] = kb[cs];
      const uint4* vb = (const uint4*)(vv + ((((size_t)bh << 12) + t) << 6));
      int sw = (cs ^ (j & 7) ^ (j >> 3)) & 7;
      *(uint4*)&Vs[j * 72 + sw * 8] = vb[cs];
      if (cs == 0) {
        float mv = load_in(mask, b * 4096 + t, f32in);
        Tkv[j] = (unsigned short)(t | ((mv != 0.0f) ? 0 : 0x8000));
        Nkv[j] = nk[((size_t)bh << 12) + t] * 0.125f;
      }
    }
    __syncthreads();

    #pragma unroll
    for (int i = 0; i < 8; ++i) {
      int cp = w * 8 + i;
      int q8 = cp >> 2;
      int sw = (q8 ^ (lane & 7) ^ (lane >> 3)) & 7;
      uint32_t wv = *(const uint32_t*)&Vs[lane * 72 + sw * 8 + ((2 * cp) & 7)];
      Vt[(2 * cp) * 72 + lane]     = (unsigned short)(wv & 0xffff);
      Vt[(2 * cp + 1) * 72 + lane] = (unsigned short)(wv >> 16);
    }

    f32x4 sacc[2][4];
    #pragma unroll
    for (int mt = 0; mt < 2; ++mt)
      #pragma unroll
      for (int nt = 0; nt < 4; ++nt) sacc[mt][nt] = (f32x4){0.f, 0.f, 0.f, 0.f};
    #pragma unroll
    for (int ks = 0; ks < 2; ++ks) {
      bf16x8 af[2];
      #pragma unroll
      for (int mt = 0; mt < 2; ++mt)
        af[mt] = *(const bf16x8*)&Qs[(w * 32 + mt * 16 + l15) * 72 + ks * 32 + lq * 8];
      #pragma unroll
      for (int nt = 0; nt < 4; ++nt) {
        bf16x8 bfr = *(const bf16x8*)&Ks[(nt * 16 + l15) * 72 + ks * 32 + lq * 8];
        #pragma unroll
        for (int mt = 0; mt < 2; ++mt)
          sacc[mt][nt] = __builtin_amdgcn_mfma_f32_16x16x32_bf16(af[mt], bfr, sacc[mt][nt], 0, 0, 0);
      }
    }

    unsigned short tkc[4];
    float nkc[4];
    #pragma unroll
    for (int nt = 0; nt < 4; ++nt) {
      tkc[nt] = Tkv[nt * 16 + l15];
      nkc[nt] = Nkv[nt * 16 + l15];
    }
    float dv[2][4][4];
    #pragma unroll
    for (int mt = 0; mt < 2; ++mt)
      #pragma unroll
      for (int nt = 0; nt < 4; ++nt)
        #pragma unroll
        for (int reg = 0; reg < 4; ++reg) {
          float x = sacc[mt][nt][reg] * nkc[nt];
          unsigned short ts = tqr[mt][reg];
          if (((tkc[nt] | ts) & 0x8000) != 0) x = -1.0e9f;
          if (((tkc[nt] ^ ts) & 0x0fff) == 0) x = -5.0e4f;
          dv[mt][nt][reg] = x;
        }
    float mn[2][4], scv[2][4];
    #pragma unroll
    for (int mt = 0; mt < 2; ++mt)
      #pragma unroll
      for (int reg = 0; reg < 4; ++reg) {
        float rm = fmaxf(fmaxf(dv[mt][0][reg], dv[mt][1][reg]),
                         fmaxf(dv[mt][2][reg], dv[mt][3][reg]));
        rm = fmaxf(rm, __shfl_xor(rm, 1, 64));
        rm = fmaxf(rm, __shfl_xor(rm, 2, 64));
        rm = fmaxf(rm, __shfl_xor(rm, 4, 64));
        rm = fmaxf(rm, __shfl_xor(rm, 8, 64));
        float mnew = fmaxf(m_run[mt][reg], rm);
        scv[mt][reg] = __expf(m_run[mt][reg] - mnew);
        m_run[mt][reg] = mnew;
        mn[mt][reg] = mnew;
      }
    #pragma unroll
    for (int mt = 0; mt < 2; ++mt)
      #pragma unroll
      for (int nt = 0; nt < 4; ++nt)
        #pragma unroll
        for (int reg = 0; reg < 4; ++reg)
          dv[mt][nt][reg] = __expf(dv[mt][nt][reg] - mn[mt][reg]);
    #pragma unroll
    for (int mt = 0; mt < 2; ++mt)
      #pragma unroll
      for (int reg = 0; reg < 4; ++reg) {
        float rs = ((dv[mt][0][reg] + dv[mt][1][reg]) + (dv[mt][2][reg] + dv[mt][3][reg]));
        rs += __shfl_xor(rs, 1, 64);
        rs += __shfl_xor(rs, 2, 64);
        rs += __shfl_xor(rs, 4, 64);
        rs += __shfl_xor(rs, 8, 64);
        l_run[mt][reg] = l_run[mt][reg] * scv[mt][reg] + rs;
      }
    #pragma unroll
    for (int mt = 0; mt < 2; ++mt)
      #pragma unroll
      for (int nto = 0; nto < 4; ++nto)
        #pragma unroll
        for (int reg = 0; reg < 4; ++reg)
          oacc[mt][nto][reg] *= scv[mt][reg];

    __syncthreads();

    #pragma unroll
    for (int mt = 0; mt < 2; ++mt)
      #pragma unroll
      for (int nt = 0; nt < 4; ++nt)
        #pragma unroll
        for (int reg = 0; reg < 4; ++reg)
          Ps[w * 2304 + (mt * 16 + lq * 4 + reg) * 72 + nt * 16 + l15] = f2bf(dv[mt][nt][reg]);

    #pragma unroll
    for (int ks = 0; ks < 2; ++ks) {
      bf16x8 pf[2];
      #pragma unroll
      for (int mt = 0; mt < 2; ++mt)
        pf[mt] = *(const bf16x8*)&Ps[w * 2304 + (mt * 16 + l15) * 72 + ks * 32 + lq * 8];
      #pragma unroll
      for (int nto = 0; nto < 4; ++nto) {
        bf16x8 vf = *(const bf16x8*)&Vt[(nto * 16 + l15) * 72 + ks * 32 + lq * 8];
        #pragma unroll
        for (int mt = 0; mt < 2; ++mt)
          oacc[mt][nto] = __builtin_amdgcn_mfma_f32_16x16x32_bf16(pf[mt], vf, oacc[mt][nto], 0, 0, 0);
      }
    }
  }

  float invl[2][4];
  #pragma unroll
  for (int mt = 0; mt < 2; ++mt)
    #pragma unroll
    for (int reg = 0; reg < 4; ++reg) {
      float lr = l_run[mt][reg];
      invl[mt][reg] = 1.0f / lr;
      if (l15 == 0) {
        int Rr = w * 32 + mt * 16 + lq * 4 + reg;
        int s = Tq[Rr];
        int tq0 = s & 4095, rq0 = (s >> 12) & 1;
        lse_r[(((size_t)(bh * 2 + rq0)) << 12) + tq0] = m_run[mt][reg] + __logf(lr);
      }
    }
  #pragma unroll
  for (int mt = 0; mt < 2; ++mt)
    #pragma unroll
    for (int nto = 0; nto < 4; ++nto)
      #pragma unroll
      for (int reg = 0; reg < 4; ++reg)
        Ps[w * 2304 + (mt * 16 + lq * 4 + reg) * 72 + nto * 16 + l15] =
            f2bf(oacc[mt][nto][reg] * invl[mt][reg]);
  #pragma unroll
  for (int pass = 0; pass < 4; ++pass) {
    int rl = pass * 8 + (lane >> 3);
    int s = Tq[w * 32 + rl];
    int tq0 = s & 4095, rq0 = (s >> 12) & 1;
    uint4 ov = *(const uint4*)&Ps[w * 2304 + rl * 72 + (lane & 7) * 8];
    *(uint4*)(o_r + ((((size_t)(bh * 2 + rq0)) << 12) + tq0) * 64 + (lane & 7) * 8) = ov;
  }
}

// ---------------------------------------------------------------- combine hash rounds
__global__ __launch_bounds__(256) void k_combine(
    const unsigned short* __restrict__ o_r,
    const float* __restrict__ lse_r,
    unsigned short* __restrict__ attn) {
  int idx = blockIdx.x * 256 + threadIdx.x;
  if (idx >= 48 * 4096 * 64) return;
  int f = idx & 63;
  int t = (idx >> 6) & 4095;
  int bh = idx >> 18;
  float l0 = lse_r[((size_t)(bh * 2 + 0) << 12) + t];
  float l1 = lse_r[((size_t)(bh * 2 + 1) << 12) + t];
  float mm = fmaxf(l0, l1);
  float e0 = __expf(l0 - mm), e1 = __expf(l1 - mm);
  float inv = 1.0f / (e0 + e1);
  float o0 = bf2f(o_r[(((size_t)(bh * 2 + 0) << 12) + t) * 64 + f]);
  float o1 = bf2f(o_r[(((size_t)(bh * 2 + 1) << 12) + t) * 64 + f]);
  float res = (e0 * o0 + e1 * o1) * inv;
  int b = bh / 12, hh = bh % 12;
  attn[((size_t)(b * 4096 + t)) * 768 + hh * 64 + f] = f2bf(res);
}

extern "C" void kernel_launch(void* const* d_in, const int* in_sizes, int n_in,
                              void* d_out, int out_size, void* d_ws, size_t ws_size,
                              hipStream_t stream) {
  (void)in_sizes; (void)n_in; (void)out_size; (void)ws_size;
  const void* X    = d_in[0];
  const void* mask = d_in[1];
  const void* Wqk  = d_in[2];
  const void* Wv   = d_in[3];
  const void* rot  = d_in[4];
  const void* Wto  = d_in[5];
  const void* bto  = d_in[6];
  const void* Wo   = d_in[7];
  const void* bo   = d_in[8];

  char* ws = (char*)d_ws;
  int*            flag  = (int*)(ws);
  unsigned short* stick = (unsigned short*)(ws + 256);
  float*          lse_r = (float*)(ws + 786688);
  float*          nk    = (float*)(ws + 2359552);
  unsigned short* qk    = (unsigned short*)(ws + 3145984);
  unsigned short* v     = (unsigned short*)(ws + 28311808);
  unsigned short* o_r   = (unsigned short*)(ws + 53477632);
  double*         WrotT = (double*)(ws + 53477632);
  unsigned char*  cls   = (unsigned char*)(ws + 55836928);
  unsigned short* Wqkb  = (unsigned short*)(ws + 56230144);
  unsigned short* Wvb   = (unsigned short*)(ws + 57409792);
  unsigned short* Xb    = (unsigned short*)(ws + 58589440);
  unsigned short* Wtob  = (unsigned short*)(ws + 53477632);
  unsigned short* Wob   = (unsigned short*)(ws + 54657280);
  unsigned short* attn  = v;
  unsigned short* tmp   = qk;

  k_detect<<<1, 64, 0, stream>>>((const unsigned int*)X, flag);
  k_convert<<<49152, 256, 0, stream>>>(X, Xb, 12582912, flag);
  k_convert<<<2304, 256, 0, stream>>>(Wqk, Wqkb, 589824, flag);
  k_convert<<<2304, 256, 0, stream>>>(Wv, Wvb, 589824, flag);
  k_build_wrot<<<1152, 256, 0, stream>>>(Wqk, rot, WrotT, flag);
  k_bucket<<<1024, 384, 0, stream>>>(X, WrotT, cls, flag);
  k_sort<<<48, 1024, 0, stream>>>(cls, stick);
  k_gemm_mfma<<<dim3(128, 6), 256, 0, stream>>>(Xb, Wqkb, nullptr, qk, 1, 0, flag);
  k_gemm_mfma<<<dim3(128, 6), 256, 0, stream>>>(Xb, Wvb,  nullptr, v,  1, 0, flag);
  k_norm<<<6144, 256, 0, stream>>>(qk, nk);
  k_attn_mfma<<<3072, 256, 0, stream>>>(qk, v, stick, mask, nk, o_r, lse_r, flag);
  k_combine<<<49152, 256, 0, stream>>>(o_r, lse_r, attn);
  k_convert<<<2304, 256, 0, stream>>>(Wto, Wtob, 589824, flag);
  k_convert<<<2304, 256, 0, stream>>>(Wo, Wob, 589824, flag);
  k_gemm_mfma<<<dim3(128, 6), 256, 0, stream>>>(attn, Wtob, bto, tmp, 0, 0, flag);
  k_gemm_mfma<<<dim3(128, 6), 256, 0, stream>>>(tmp, Wob, bo, d_out, 0, 1, flag);
}

// Round 5
// 696.914 us; speedup vs baseline: 4.5147x; 1.3718x over previous
//
#include <hip/hip_runtime.h>
#include <hip/hip_bf16.h>
#include <math.h>

// ReformerAttention (LSH attention) on MI355X — MFMA + parallel sort + f64-GEMM bucket.
// B=4 T=4096 HID=768 H=12 D=64 n_hashes=2 n_buckets=32 bucket=128.
//
// Workspace layout (bytes), peak 103,809,280:
//   0           flag   256
//   256         stick  u16[48][8192]        786,432
//   786,688     lse_r  f32[48*2][4096]    1,572,864
//   2,359,552   nk     f32[48][4096]        786,432
//   3,145,984   qk     bf16[48][4096][64] 25,165,824   (later tmp)
//   28,311,808  v      bf16[48][4096][64] 25,165,824   (later attn)
//   53,477,632  o_r    bf16[96][4096][64] 50,331,648
//   overlays inside o_r (dead before k_attn): WrotT/cls/Wqkb/Wvb/Xb
//   after k_combine: Wtob/Wob

typedef __attribute__((ext_vector_type(8))) short bf16x8;
typedef __attribute__((ext_vector_type(4))) float f32x4;

__device__ __forceinline__ float bf_lo(unsigned int w) { return __uint_as_float(w << 16); }
__device__ __forceinline__ float bf_hi(unsigned int w) { return __uint_as_float(w & 0xffff0000u); }
__device__ __forceinline__ float load_in(const void* p, size_t i, bool f32) {
  return f32 ? ((const float*)p)[i]
             : __bfloat162float(((const __hip_bfloat16*)p)[i]);
}
__device__ __forceinline__ unsigned short f2bf(float x) {
  __hip_bfloat16 h = __float2bfloat16(x);
  return *reinterpret_cast<unsigned short*>(&h);
}
__device__ __forceinline__ float bf2f(unsigned short u) { return __uint_as_float(((unsigned int)u) << 16); }

// ---------------------------------------------------------------- dtype detect
__global__ void k_detect(const unsigned int* __restrict__ X, int* __restrict__ flag) {
  if (threadIdx.x == 0 && blockIdx.x == 0) {
    int vote = 0;
    for (int i = 0; i < 64; ++i) {
      unsigned int e = (X[i] >> 7) & 0xffu;
      vote += (e >= 100u && e <= 141u) ? 1 : 0;
    }
    *flag = (vote < 32) ? 1 : 0;   // 1 => inputs are f32
  }
}

// ---------------------------------------------------------------- convert input -> bf16
__global__ __launch_bounds__(256) void k_convert(
    const void* __restrict__ src, unsigned short* __restrict__ dst, int n,
    const int* __restrict__ flag) {
  const bool f32in = (*flag != 0);
  int i = blockIdx.x * 256 + threadIdx.x;
  if (i >= n) return;
  if (f32in) dst[i] = f2bf(((const float*)src)[i]);
  else       dst[i] = ((const unsigned short*)src)[i];
}

// ---------------------------------------------------------------- fold rotations (f64)
__global__ __launch_bounds__(256) void k_build_wrot(
    const void* __restrict__ Wqk, const void* __restrict__ rot,
    double* __restrict__ WrotT, const int* __restrict__ flag) {
  const bool f32in = (*flag != 0);
  int idx = blockIdx.x * 256 + threadIdx.x;
  if (idx >= 768 * 384) return;
  int row = idx % 384;
  int c   = idx / 384;
  int hh = row >> 5, hi = row & 31;
  double s = 0.0;
  for (int f = 0; f < 64; ++f) {
    double rv = (double)load_in(rot, f * 32 + hi, f32in);
    double wv = (double)load_in(Wqk, (size_t)(hh * 64 + f) * 768 + c, f32in);
    s = fma(rv, wv, s);
  }
  WrotT[(size_t)c * 384 + row] = s;
}

// ---------------------------------------------------------------- bucket scores (f64 GEMM) + argmax
// Scores[m][n] = sum_k X[m][k] * WrotT[k][n]; k strictly ascending per
// accumulator => bit-identical to prior passing rounds. BM=128 BN=96 BK=16,
// 256 thr, thread tile 8 tokens x 6 rows. Grid 128x4 = 512 blocks (2/CU).
__global__ __launch_bounds__(256) void k_bucket(
    const void* __restrict__ X, const double* __restrict__ WrotT,
    unsigned char* __restrict__ cls, const int* __restrict__ flag) {
  const bool f32in = (*flag != 0);
  __shared__ double SH[6336];          // 50,688 B
  double* Xs = SH;                     // [16][130]
  double* Ws = SH + 2080;              // [16][98]
  double* Sc = SH;                     // [96][66]  (epilogue union)
  const int tid = threadIdx.x;
  const int M0 = blockIdx.x * 128;
  const int N0 = blockIdx.y * 96;
  const int tm = tid >> 4, tn = tid & 15;
  const int sr = tid >> 1, sh = tid & 1;     // X staging: row, k-half
  const int wk = tid >> 4, wg = tid & 15;    // W staging: k-row, group

  double acc[8][6];
  #pragma unroll
  for (int i = 0; i < 8; ++i)
    #pragma unroll
    for (int j = 0; j < 6; ++j) acc[i][j] = 0.0;

  for (int k0 = 0; k0 < 768; k0 += 16) {
    __syncthreads();
    {  // stage X -> Xs[k][m] (transposed, converted to f64)
      size_t base = (size_t)(M0 + sr) * 768 + k0 + sh * 8;
      double xv[8];
      if (f32in) {
        const float4* fp = (const float4*)((const float*)X + base);
        float4 f0 = fp[0], f1 = fp[1];
        xv[0] = f0.x; xv[1] = f0.y; xv[2] = f0.z; xv[3] = f0.w;
        xv[4] = f1.x; xv[5] = f1.y; xv[6] = f1.z; xv[7] = f1.w;
      } else {
        uint4 u = *(const uint4*)((const unsigned short*)X + base);
        xv[0] = (double)bf_lo(u.x); xv[1] = (double)bf_hi(u.x);
        xv[2] = (double)bf_lo(u.y); xv[3] = (double)bf_hi(u.y);
        xv[4] = (double)bf_lo(u.z); xv[5] = (double)bf_hi(u.z);
        xv[6] = (double)bf_lo(u.w); xv[7] = (double)bf_hi(u.w);
      }
      #pragma unroll
      for (int j = 0; j < 8; ++j) Xs[(sh * 8 + j) * 130 + sr] = xv[j];
    }
    {  // stage WrotT -> Ws[k][n]
      const double* wp = WrotT + (size_t)(k0 + wk) * 384 + N0 + wg * 6;
      #pragma unroll
      for (int e = 0; e < 6; ++e) Ws[wk * 98 + wg * 6 + e] = wp[e];
    }
    __syncthreads();
    #pragma unroll
    for (int k = 0; k < 16; ++k) {
      double a_[8], b_[6];
      #pragma unroll
      for (int i = 0; i < 8; ++i) a_[i] = Xs[k * 130 + tm * 8 + i];
      #pragma unroll
      for (int j = 0; j < 6; ++j) b_[j] = Ws[k * 98 + tn * 6 + j];
      #pragma unroll
      for (int i = 0; i < 8; ++i)
        #pragma unroll
        for (int j = 0; j < 6; ++j)
          acc[i][j] = fma(a_[i], b_[j], acc[i][j]);
    }
  }

  // epilogue: two 64-token chunks through Sc, then first-index-wins argmax
  #pragma unroll
  for (int chunk = 0; chunk < 2; ++chunk) {
    __syncthreads();
    if ((tm >> 3) == chunk) {
      #pragma unroll
      for (int tt = 0; tt < 8; ++tt)
        #pragma unroll
        for (int rr = 0; rr < 6; ++rr)
          Sc[(tn * 6 + rr) * 66 + (tm & 7) * 8 + tt] = acc[tt][rr];
    }
    __syncthreads();
    for (int task = tid; task < 384; task += 256) {
      int g = task >> 6, tok = task & 63;
      const double* s = &Sc[(g * 16) * 66 + tok];
      double mx = -1.0e300;
      #pragma unroll
      for (int i = 0; i < 16; ++i) {
        double a = s[i * 66];
        mx = fmax(mx, fmax(a, -a));
      }
      int amax = 0;
      #pragma unroll
      for (int i = 15; i >= 0; --i) if (-s[i * 66] == mx) amax = 16 + i;
      #pragma unroll
      for (int i = 15; i >= 0; --i) if (s[i * 66] == mx) amax = i;
      int m = M0 + chunk * 64 + tok;
      int b = m >> 12, t = m & 4095;
      int gg = blockIdx.y * 6 + g, hh = gg >> 1, h = gg & 1;
      cls[(size_t)(b * 12 + hh) * 8192 + h * 4096 + t] = (unsigned char)(h * 32 + amax);
    }
  }
}

// ---------------------------------------------------------------- parallel stable counting sort
__global__ __launch_bounds__(1024) void k_sort(
    const unsigned char* __restrict__ clsg,
    unsigned short* __restrict__ stick) {
  __shared__ unsigned short cntg[128 * 64];
  __shared__ int classbase[64];
  const int row = blockIdx.x;
  const int tid = threadIdx.x;
  const int wave = tid >> 6, lane = tid & 63;
  const unsigned char* cr = clsg + ((size_t)row << 13);

  for (int i = tid; i < 128 * 64 / 2; i += 1024) ((uint32_t*)cntg)[i] = 0;
  __syncthreads();

  unsigned char myc[8], myrank[8];
  const unsigned long long ltmask = (lane == 0) ? 0ull : (~0ull >> (64 - lane));
  #pragma unroll
  for (int chunk = 0; chunk < 8; ++chunk) {
    int g = chunk * 16 + wave;
    int j = g * 64 + lane;
    int c = cr[j];
    unsigned long long same = ~0ull;
    #pragma unroll
    for (int bit = 0; bit < 6; ++bit) {
      unsigned long long bm = __ballot((c >> bit) & 1);
      same &= ((c >> bit) & 1) ? bm : ~bm;
    }
    int rank = __popcll(same & ltmask);
    if (rank == 0) cntg[g * 64 + c] = (unsigned short)__popcll(same);
    myc[chunk] = (unsigned char)c;
    myrank[chunk] = (unsigned char)rank;
  }
  __syncthreads();
  if (tid < 64) {
    int run = 0;
    for (int g = 0; g < 128; ++g) {
      int t = cntg[g * 64 + tid];
      cntg[g * 64 + tid] = (unsigned short)run;
      run += t;
    }
    classbase[tid] = run;
  }
  __syncthreads();
  if (tid == 0) {
    int run = 0;
    for (int c = 0; c < 64; ++c) { int t = classbase[c]; classbase[c] = run; run += t; }
  }
  __syncthreads();
  unsigned short* out = stick + ((size_t)row << 13);
  #pragma unroll
  for (int chunk = 0; chunk < 8; ++chunk) {
    int g = chunk * 16 + wave;
    int j = g * 64 + lane;
    int c = myc[chunk];
    int pos = classbase[c] + cntg[g * 64 + c] + myrank[chunk];
    out[pos] = (unsigned short)j;
  }
}

// ---------------------------------------------------------------- MFMA GEMM, K=768
__global__ __launch_bounds__(256) void k_gemm_mfma(
    const unsigned short* __restrict__ A, const unsigned short* __restrict__ W,
    const void* __restrict__ bias, void* __restrict__ Cout,
    int layout, int out_ext, const int* __restrict__ flag) {
  const bool f32in = (*flag != 0);
  const bool oF32 = out_ext && f32in;
  __shared__ unsigned short As[128 * 40];
  __shared__ unsigned short Bs[128 * 40];
  const int tid = threadIdx.x;
  const int bm = blockIdx.x, bn = blockIdx.y;
  const int w = tid >> 6, lane = tid & 63;
  const int l15 = lane & 15, lq = lane >> 4;
  const int wm = (w >> 1) * 64, wn = (w & 1) * 64;
  const int r4 = tid >> 2, c4 = tid & 3;
  const unsigned short* Ag = A + (size_t)(bm * 128 + r4) * 768 + c4 * 8;
  const unsigned short* Bg = W + (size_t)(bn * 128 + r4) * 768 + c4 * 8;
  f32x4 acc[4][4];
  #pragma unroll
  for (int i = 0; i < 4; ++i)
    #pragma unroll
    for (int j = 0; j < 4; ++j) acc[i][j] = (f32x4){0.f, 0.f, 0.f, 0.f};
  uint4 pa0 = *(const uint4*)(Ag);
  uint4 pa1 = *(const uint4*)(Ag + 64 * 768);
  uint4 pb0 = *(const uint4*)(Bg);
  uint4 pb1 = *(const uint4*)(Bg + 64 * 768);
  for (int kt = 0; kt < 24; ++kt) {
    __syncthreads();
    *(uint4*)&As[r4 * 40 + c4 * 8] = pa0;
    *(uint4*)&As[(r4 + 64) * 40 + c4 * 8] = pa1;
    *(uint4*)&Bs[r4 * 40 + c4 * 8] = pb0;
    *(uint4*)&Bs[(r4 + 64) * 40 + c4 * 8] = pb1;
    __syncthreads();
    if (kt < 23) {
      int off = (kt + 1) * 32;
      pa0 = *(const uint4*)(Ag + off);
      pa1 = *(const uint4*)(Ag + 64 * 768 + off);
      pb0 = *(const uint4*)(Bg + off);
      pb1 = *(const uint4*)(Bg + 64 * 768 + off);
    }
    bf16x8 af[4], bfr[4];
    #pragma unroll
    for (int mt = 0; mt < 4; ++mt)
      af[mt] = *(const bf16x8*)&As[(wm + mt * 16 + l15) * 40 + lq * 8];
    #pragma unroll
    for (int nt = 0; nt < 4; ++nt)
      bfr[nt] = *(const bf16x8*)&Bs[(wn + nt * 16 + l15) * 40 + lq * 8];
    #pragma unroll
    for (int mt = 0; mt < 4; ++mt)
      #pragma unroll
      for (int nt = 0; nt < 4; ++nt)
        acc[mt][nt] = __builtin_amdgcn_mfma_f32_16x16x32_bf16(af[mt], bfr[nt], acc[mt][nt], 0, 0, 0);
  }
  #pragma unroll
  for (int mt = 0; mt < 4; ++mt) {
    #pragma unroll
    for (int nt = 0; nt < 4; ++nt) {
      #pragma unroll
      for (int reg = 0; reg < 4; ++reg) {
        int m = bm * 128 + wm + mt * 16 + lq * 4 + reg;
        int n = bn * 128 + wn + nt * 16 + l15;
        float val = acc[mt][nt][reg];
        if (bias != nullptr) val += load_in(bias, n, f32in);
        if (layout == 0) {
          size_t addr = (size_t)m * 768 + n;
          if (oF32) ((float*)Cout)[addr] = val;
          else      ((unsigned short*)Cout)[addr] = f2bf(val);
        } else {
          int b2 = m >> 12, t2 = m & 4095, hh = n >> 6, f = n & 63;
          ((unsigned short*)Cout)[((((size_t)(b2 * 12 + hh)) << 12) + t2) * 64 + f] = f2bf(val);
        }
      }
    }
  }
}

// ---------------------------------------------------------------- key norms
__global__ __launch_bounds__(256) void k_norm(
    const unsigned short* __restrict__ qk, float* __restrict__ nk) {
  int row = blockIdx.x * 32 + (threadIdx.x >> 3);
  int cs = threadIdx.x & 7;
  const uint4* p = (const uint4*)(qk + (size_t)row * 64);
  uint4 wv = p[cs];
  float s = 0.f;
  float e;
  e = bf_lo(wv.x); s += e * e;  e = bf_hi(wv.x); s += e * e;
  e = bf_lo(wv.y); s += e * e;  e = bf_hi(wv.y); s += e * e;
  e = bf_lo(wv.z); s += e * e;  e = bf_hi(wv.z); s += e * e;
  e = bf_lo(wv.w); s += e * e;  e = bf_hi(wv.w); s += e * e;
  s += __shfl_xor(s, 1, 64);
  s += __shfl_xor(s, 2, 64);
  s += __shfl_xor(s, 4, 64);
  if (cs == 0) nk[row] = 1.0f / fmaxf(sqrtf(s), 1e-12f);
}

// ---------------------------------------------------------------- MFMA LSH attention
__global__ __launch_bounds__(256) void k_attn_mfma(
    const unsigned short* __restrict__ qk,
    const unsigned short* __restrict__ vv,
    const unsigned short* __restrict__ stick,
    const void* __restrict__ mask,
    const float* __restrict__ nk,
    unsigned short* __restrict__ o_r,
    float* __restrict__ lse_r,
    const int* __restrict__ flag) {
  const bool f32in = (*flag != 0);
  __shared__ unsigned short Qs[128 * 72];
  __shared__ unsigned short Ks[64 * 72];
  __shared__ unsigned short Vt[64 * 72];
  __shared__ unsigned short Ps[4 * 32 * 72];
  __shared__ unsigned short Tq[128];
  __shared__ unsigned short Tkv[64];
  __shared__ float Nkv[64];
  unsigned short* Vs = Ps;

  const int tid = threadIdx.x;
  const int bh = blockIdx.x >> 6;
  const int ci = blockIdx.x & 63;
  const int b  = bh / 12;
  const int prev = (ci + 63) & 63;
  const int w = tid >> 6, lane = tid & 63;
  const int l15 = lane & 15, lq = lane >> 4;
  const unsigned short* srow = stick + ((size_t)bh << 13);
  const int jrow = tid >> 3, cs = tid & 7;

  #pragma unroll
  for (int pass = 0; pass < 4; ++pass) {
    int r = jrow + pass * 32;
    int s = srow[ci * 128 + r];
    int t = s & 4095;
    uint4 qw = ((const uint4*)(qk + ((((size_t)bh << 12) + t) << 6)))[cs];
    *(uint4*)&Qs[r * 72 + cs * 8] = qw;
    if (cs == 0) {
      float mv = load_in(mask, b * 4096 + t, f32in);
      Tq[r] = (unsigned short)(s | ((mv != 0.0f) ? 0 : 0x8000));
    }
  }
  __syncthreads();

  unsigned short tqr[2][4];
  #pragma unroll
  for (int mt = 0; mt < 2; ++mt)
    #pragma unroll
    for (int reg = 0; reg < 4; ++reg)
      tqr[mt][reg] = Tq[w * 32 + mt * 16 + lq * 4 + reg];

  float m_run[2][4], l_run[2][4];
  f32x4 oacc[2][4];
  #pragma unroll
  for (int mt = 0; mt < 2; ++mt)
    #pragma unroll
    for (int reg = 0; reg < 4; ++reg) { m_run[mt][reg] = -3.0e38f; l_run[mt][reg] = 0.0f; }
  #pragma unroll
  for (int mt = 0; mt < 2; ++mt)
    #pragma unroll
    for (int nto = 0; nto < 4; ++nto) oacc[mt][nto] = (f32x4){0.f, 0.f, 0.f, 0.f};

  for (int kt = 0; kt < 4; ++kt) {
    __syncthreads();
    #pragma unroll
    for (int pass = 0; pass < 2; ++pass) {
      int j = jrow + pass * 32;
      int chunk = (kt < 2) ? ci : prev;
      int s = srow[chunk * 128 + (kt & 1) * 64 + j];
      int t = s & 4095;
      const uint4* kb = (const uint4*)(qk + ((((size_t)bh << 12) + t) << 6));
      *(uint4*)&Ks[j * 72 + cs * 8] = kb[cs];
      const uint4* vb = (const uint4*)(vv + ((((size_t)bh << 12) + t) << 6));
      int sw = (cs ^ (j & 7) ^ (j >> 3)) & 7;
      *(uint4*)&Vs[j * 72 + sw * 8] = vb[cs];
      if (cs == 0) {
        float mv = load_in(mask, b * 4096 + t, f32in);
        Tkv[j] = (unsigned short)(t | ((mv != 0.0f) ? 0 : 0x8000));
        Nkv[j] = nk[((size_t)bh << 12) + t] * 0.125f;
      }
    }
    __syncthreads();

    #pragma unroll
    for (int i = 0; i < 8; ++i) {
      int cp = w * 8 + i;
      int q8 = cp >> 2;
      int sw = (q8 ^ (lane & 7) ^ (lane >> 3)) & 7;
      uint32_t wv = *(const uint32_t*)&Vs[lane * 72 + sw * 8 + ((2 * cp) & 7)];
      Vt[(2 * cp) * 72 + lane]     = (unsigned short)(wv & 0xffff);
      Vt[(2 * cp + 1) * 72 + lane] = (unsigned short)(wv >> 16);
    }

    f32x4 sacc[2][4];
    #pragma unroll
    for (int mt = 0; mt < 2; ++mt)
      #pragma unroll
      for (int nt = 0; nt < 4; ++nt) sacc[mt][nt] = (f32x4){0.f, 0.f, 0.f, 0.f};
    #pragma unroll
    for (int ks = 0; ks < 2; ++ks) {
      bf16x8 af[2];
      #pragma unroll
      for (int mt = 0; mt < 2; ++mt)
        af[mt] = *(const bf16x8*)&Qs[(w * 32 + mt * 16 + l15) * 72 + ks * 32 + lq * 8];
      #pragma unroll
      for (int nt = 0; nt < 4; ++nt) {
        bf16x8 bfr = *(const bf16x8*)&Ks[(nt * 16 + l15) * 72 + ks * 32 + lq * 8];
        #pragma unroll
        for (int mt = 0; mt < 2; ++mt)
          sacc[mt][nt] = __builtin_amdgcn_mfma_f32_16x16x32_bf16(af[mt], bfr, sacc[mt][nt], 0, 0, 0);
      }
    }

    unsigned short tkc[4];
    float nkc[4];
    #pragma unroll
    for (int nt = 0; nt < 4; ++nt) {
      tkc[nt] = Tkv[nt * 16 + l15];
      nkc[nt] = Nkv[nt * 16 + l15];
    }
    float dv[2][4][4];
    #pragma unroll
    for (int mt = 0; mt < 2; ++mt)
      #pragma unroll
      for (int nt = 0; nt < 4; ++nt)
        #pragma unroll
        for (int reg = 0; reg < 4; ++reg) {
          float x = sacc[mt][nt][reg] * nkc[nt];
          unsigned short ts = tqr[mt][reg];
          if (((tkc[nt] | ts) & 0x8000) != 0) x = -1.0e9f;
          if (((tkc[nt] ^ ts) & 0x0fff) == 0) x = -5.0e4f;
          dv[mt][nt][reg] = x;
        }
    float mn[2][4], scv[2][4];
    #pragma unroll
    for (int mt = 0; mt < 2; ++mt)
      #pragma unroll
      for (int reg = 0; reg < 4; ++reg) {
        float rm = fmaxf(fmaxf(dv[mt][0][reg], dv[mt][1][reg]),
                         fmaxf(dv[mt][2][reg], dv[mt][3][reg]));
        rm = fmaxf(rm, __shfl_xor(rm, 1, 64));
        rm = fmaxf(rm, __shfl_xor(rm, 2, 64));
        rm = fmaxf(rm, __shfl_xor(rm, 4, 64));
        rm = fmaxf(rm, __shfl_xor(rm, 8, 64));
        float mnew = fmaxf(m_run[mt][reg], rm);
        scv[mt][reg] = __expf(m_run[mt][reg] - mnew);
        m_run[mt][reg] = mnew;
        mn[mt][reg] = mnew;
      }
    #pragma unroll
    for (int mt = 0; mt < 2; ++mt)
      #pragma unroll
      for (int nt = 0; nt < 4; ++nt)
        #pragma unroll
        for (int reg = 0; reg < 4; ++reg)
          dv[mt][nt][reg] = __expf(dv[mt][nt][reg] - mn[mt][reg]);
    #pragma unroll
    for (int mt = 0; mt < 2; ++mt)
      #pragma unroll
      for (int reg = 0; reg < 4; ++reg) {
        float rs = ((dv[mt][0][reg] + dv[mt][1][reg]) + (dv[mt][2][reg] + dv[mt][3][reg]));
        rs += __shfl_xor(rs, 1, 64);
        rs += __shfl_xor(rs, 2, 64);
        rs += __shfl_xor(rs, 4, 64);
        rs += __shfl_xor(rs, 8, 64);
        l_run[mt][reg] = l_run[mt][reg] * scv[mt][reg] + rs;
      }
    #pragma unroll
    for (int mt = 0; mt < 2; ++mt)
      #pragma unroll
      for (int nto = 0; nto < 4; ++nto)
        #pragma unroll
        for (int reg = 0; reg < 4; ++reg)
          oacc[mt][nto][reg] *= scv[mt][reg];

    __syncthreads();

    #pragma unroll
    for (int mt = 0; mt < 2; ++mt)
      #pragma unroll
      for (int nt = 0; nt < 4; ++nt)
        #pragma unroll
        for (int reg = 0; reg < 4; ++reg)
          Ps[w * 2304 + (mt * 16 + lq * 4 + reg) * 72 + nt * 16 + l15] = f2bf(dv[mt][nt][reg]);

    #pragma unroll
    for (int ks = 0; ks < 2; ++ks) {
      bf16x8 pf[2];
      #pragma unroll
      for (int mt = 0; mt < 2; ++mt)
        pf[mt] = *(const bf16x8*)&Ps[w * 2304 + (mt * 16 + l15) * 72 + ks * 32 + lq * 8];
      #pragma unroll
      for (int nto = 0; nto < 4; ++nto) {
        bf16x8 vf = *(const bf16x8*)&Vt[(nto * 16 + l15) * 72 + ks * 32 + lq * 8];
        #pragma unroll
        for (int mt = 0; mt < 2; ++mt)
          oacc[mt][nto] = __builtin_amdgcn_mfma_f32_16x16x32_bf16(pf[mt], vf, oacc[mt][nto], 0, 0, 0);
      }
    }
  }

  float invl[2][4];
  #pragma unroll
  for (int mt = 0; mt < 2; ++mt)
    #pragma unroll
    for (int reg = 0; reg < 4; ++reg) {
      float lr = l_run[mt][reg];
      invl[mt][reg] = 1.0f / lr;
      if (l15 == 0) {
        int Rr = w * 32 + mt * 16 + lq * 4 + reg;
        int s = Tq[Rr];
        int tq0 = s & 4095, rq0 = (s >> 12) & 1;
        lse_r[(((size_t)(bh * 2 + rq0)) << 12) + tq0] = m_run[mt][reg] + __logf(lr);
      }
    }
  #pragma unroll
  for (int mt = 0; mt < 2; ++mt)
    #pragma unroll
    for (int nto = 0; nto < 4; ++nto)
      #pragma unroll
      for (int reg = 0; reg < 4; ++reg)
        Ps[w * 2304 + (mt * 16 + lq * 4 + reg) * 72 + nto * 16 + l15] =
            f2bf(oacc[mt][nto][reg] * invl[mt][reg]);
  #pragma unroll
  for (int pass = 0; pass < 4; ++pass) {
    int rl = pass * 8 + (lane >> 3);
    int s = Tq[w * 32 + rl];
    int tq0 = s & 4095, rq0 = (s >> 12) & 1;
    uint4 ov = *(const uint4*)&Ps[w * 2304 + rl * 72 + (lane & 7) * 8];
    *(uint4*)(o_r + ((((size_t)(bh * 2 + rq0)) << 12) + tq0) * 64 + (lane & 7) * 8) = ov;
  }
}

// ---------------------------------------------------------------- combine hash rounds
__global__ __launch_bounds__(256) void k_combine(
    const unsigned short* __restrict__ o_r,
    const float* __restrict__ lse_r,
    unsigned short* __restrict__ attn) {
  int idx = blockIdx.x * 256 + threadIdx.x;
  if (idx >= 48 * 4096 * 64) return;
  int f = idx & 63;
  int t = (idx >> 6) & 4095;
  int bh = idx >> 18;
  float l0 = lse_r[((size_t)(bh * 2 + 0) << 12) + t];
  float l1 = lse_r[((size_t)(bh * 2 + 1) << 12) + t];
  float mm = fmaxf(l0, l1);
  float e0 = __expf(l0 - mm), e1 = __expf(l1 - mm);
  float inv = 1.0f / (e0 + e1);
  float o0 = bf2f(o_r[(((size_t)(bh * 2 + 0) << 12) + t) * 64 + f]);
  float o1 = bf2f(o_r[(((size_t)(bh * 2 + 1) << 12) + t) * 64 + f]);
  float res = (e0 * o0 + e1 * o1) * inv;
  int b = bh / 12, hh = bh % 12;
  attn[((size_t)(b * 4096 + t)) * 768 + hh * 64 + f] = f2bf(res);
}

extern "C" void kernel_launch(void* const* d_in, const int* in_sizes, int n_in,
                              void* d_out, int out_size, void* d_ws, size_t ws_size,
                              hipStream_t stream) {
  (void)in_sizes; (void)n_in; (void)out_size; (void)ws_size;
  const void* X    = d_in[0];
  const void* mask = d_in[1];
  const void* Wqk  = d_in[2];
  const void* Wv   = d_in[3];
  const void* rot  = d_in[4];
  const void* Wto  = d_in[5];
  const void* bto  = d_in[6];
  const void* Wo   = d_in[7];
  const void* bo   = d_in[8];

  char* ws = (char*)d_ws;
  int*            flag  = (int*)(ws);
  unsigned short* stick = (unsigned short*)(ws + 256);
  float*          lse_r = (float*)(ws + 786688);
  float*          nk    = (float*)(ws + 2359552);
  unsigned short* qk    = (unsigned short*)(ws + 3145984);
  unsigned short* v     = (unsigned short*)(ws + 28311808);
  unsigned short* o_r   = (unsigned short*)(ws + 53477632);
  double*         WrotT = (double*)(ws + 53477632);
  unsigned char*  cls   = (unsigned char*)(ws + 55836928);
  unsigned short* Wqkb  = (unsigned short*)(ws + 56230144);
  unsigned short* Wvb   = (unsigned short*)(ws + 57409792);
  unsigned short* Xb    = (unsigned short*)(ws + 58589440);
  unsigned short* Wtob  = (unsigned short*)(ws + 53477632);
  unsigned short* Wob   = (unsigned short*)(ws + 54657280);
  unsigned short* attn  = v;
  unsigned short* tmp   = qk;

  k_detect<<<1, 64, 0, stream>>>((const unsigned int*)X, flag);
  k_convert<<<49152, 256, 0, stream>>>(X, Xb, 12582912, flag);
  k_convert<<<2304, 256, 0, stream>>>(Wqk, Wqkb, 589824, flag);
  k_convert<<<2304, 256, 0, stream>>>(Wv, Wvb, 589824, flag);
  k_build_wrot<<<1152, 256, 0, stream>>>(Wqk, rot, WrotT, flag);
  k_bucket<<<dim3(128, 4), 256, 0, stream>>>(X, WrotT, cls, flag);
  k_sort<<<48, 1024, 0, stream>>>(cls, stick);
  k_gemm_mfma<<<dim3(128, 6), 256, 0, stream>>>(Xb, Wqkb, nullptr, qk, 1, 0, flag);
  k_gemm_mfma<<<dim3(128, 6), 256, 0, stream>>>(Xb, Wvb,  nullptr, v,  1, 0, flag);
  k_norm<<<6144, 256, 0, stream>>>(qk, nk);
  k_attn_mfma<<<3072, 256, 0, stream>>>(qk, v, stick, mask, nk, o_r, lse_r, flag);
  k_combine<<<49152, 256, 0, stream>>>(o_r, lse_r, attn);
  k_convert<<<2304, 256, 0, stream>>>(Wto, Wtob, 589824, flag);
  k_convert<<<2304, 256, 0, stream>>>(Wo, Wob, 589824, flag);
  k_gemm_mfma<<<dim3(128, 6), 256, 0, stream>>>(attn, Wtob, bto, tmp, 0, 0, flag);
  k_gemm_mfma<<<dim3(128, 6), 256, 0, stream>>>(tmp, Wob, bo, d_out, 0, 1, flag);
}